// Round 7
// baseline (360.271 us; speedup 1.0000x reference)
//
#include <hip/hip_runtime.h>
#include <cstdint>

#define BB 8
#define NN 16384
#define DD 128
#define KK 10
#define N_ITERS 7
#define LN_EPS 1e-5f
#define ATT_EPS 1e-8f

#define LNR 32                 // rows per ln_kv block
#define LNCH (NN / LNR)        // 512 chunks per batch
#define NB 128                 // n per attn block
#define NCH (NN / NB)          // 128 chunks per batch

typedef __attribute__((ext_vector_type(8))) short bf16x8;
typedef __attribute__((ext_vector_type(4))) float f32x4;

__device__ inline ushort f2bf(float f) {
    uint u = __builtin_bit_cast(uint, f);
    u += 0x7FFFu + ((u >> 16) & 1u);
    return (ushort)(u >> 16);
}
__device__ inline float bf2f(ushort u) {
    return __builtin_bit_cast(float, ((uint)u) << 16);
}

// ---- workspace layout (float units; bf16 arrays use 2 per float) ----
// kR: K row-major [B][N][D] bf16 ; vT: V transposed [B][D][N] bf16
// upart: [B][K][NCH][D]  (dense per (b,k) for k_slot streaming reduce)
// dpart: [B][K][NCH]
#define OFF_KR    ((size_t)0)
#define OFF_VT    (OFF_KR + (size_t)BB * NN * DD / 2)
#define OFF_WKVF  (OFF_VT + (size_t)BB * DD * NN / 2)       // ushort[32768]
#define OFF_Q     (OFF_WKVF + 16384)
#define OFF_SLOTS (OFF_Q + (size_t)BB * KK * DD)
#define OFF_UPART (OFF_SLOTS + (size_t)BB * KK * DD)
#define OFF_DPART (OFF_UPART + (size_t)BB * KK * NCH * DD)
#define OFF_SVP   (OFF_DPART + (size_t)BB * KK * NCH)
#define OFF_SUMV  (OFF_SVP + (size_t)BB * LNCH * DD)
#define OFF_WIHT  (OFF_SUMV + (size_t)BB * DD)
#define OFF_WHHT  (OFF_WIHT + (size_t)3 * DD * DD)

// ------------------------------------------------------------------
// Prep: WihT/WhhT transposes (fp32) + Wkv fragment-order bf16 pack.
// WkvF: ((ct*4+ks)*64+lane)*8+j holds B[k][col], col=ct*16+(lane&15),
// k=ks*32+(lane>>4)*8+j; cols 0-127 = Wk, 128-255 = Wv.  (HW-verified r5)
__global__ void k_prep(const float* __restrict__ Wih, const float* __restrict__ Whh,
                       const float* __restrict__ Wk, const float* __restrict__ Wv,
                       float* __restrict__ WihT, float* __restrict__ WhhT,
                       ushort* __restrict__ WkvF) {
    int idx = blockIdx.x * 256 + threadIdx.x;
    if (idx < 3 * DD * DD) {
        int d = idx / (3 * DD);
        int j = idx % (3 * DD);
        WihT[idx] = Wih[j * DD + d];
        WhhT[idx] = Whh[j * DD + d];
    } else if (idx < 3 * DD * DD + 32768) {
        int i = idx - 3 * DD * DD;
        int jj = i & 7, l = (i >> 3) & 63, ks = (i >> 9) & 3, ct = i >> 11;
        int col = ct * 16 + (l & 15);
        int kk2 = ks * 32 + (l >> 4) * 8 + jj;
        float wv = (col < DD) ? Wk[kk2 * DD + col] : Wv[kk2 * DD + col - DD];
        WkvF[i] = f2bf(wv);
    }
}

// ------------------------------------------------------------------
// Fused LayerNorm + K/V projection via MFMA. 256 threads / 32 rows.
// Outputs: kR bf16 [B][N][D], vT bf16 [B][D][N], svp column sums of v
// (computed from accumulator regs, shfl over the n-direction lanes).
__global__ __launch_bounds__(256) void k_ln_kv(
        const float* __restrict__ x, const ushort* __restrict__ WkvF,
        const float* __restrict__ bk, const float* __restrict__ bv,
        const float* __restrict__ g_in, const float* __restrict__ b_in,
        ushort* __restrict__ kR, ushort* __restrict__ vT,
        float* __restrict__ svp) {
    __shared__ ushort xA[LNR][136];     // A tile bf16 (272B rows, 16B-aligned)
    __shared__ ushort kstR[LNR][136];   // K stage [n][col]
    __shared__ ushort vstT[DD][40];     // V stage [col][n] (80B rows, 16B-aligned)

    int t = threadIdx.x;
    int blk = blockIdx.x;
    int b  = blk >> 9;          // / LNCH
    int ch = blk & (LNCH - 1);
    int n0 = ch * LNR;

    // ---- LN: thread (r = t>>3, p = t&7) owns 16 cols of row r ----
    {
        int r = t >> 3, p = t & 7;
        const float4* xr = (const float4*)(x + ((size_t)(b * NN + n0 + r)) * DD + p * 16);
        float4 xv[4];
        float s = 0.f, sq = 0.f;
        #pragma unroll
        for (int i = 0; i < 4; i++) {
            xv[i] = xr[i];
            s  += xv[i].x + xv[i].y + xv[i].z + xv[i].w;
            sq += xv[i].x * xv[i].x + xv[i].y * xv[i].y +
                  xv[i].z * xv[i].z + xv[i].w * xv[i].w;
        }
        s += __shfl_xor(s, 1);  sq += __shfl_xor(sq, 1);
        s += __shfl_xor(s, 2);  sq += __shfl_xor(sq, 2);
        s += __shfl_xor(s, 4);  sq += __shfl_xor(sq, 4);
        float mean = s * (1.0f / DD);
        float var  = sq * (1.0f / DD) - mean * mean;
        float rstd = rsqrtf(var + LN_EPS);
        #pragma unroll
        for (int i = 0; i < 4; i++) {
            int c0 = p * 16 + i * 4;
            ushort4 uv;
            uv.x = f2bf((xv[i].x - mean) * rstd * g_in[c0 + 0] + b_in[c0 + 0]);
            uv.y = f2bf((xv[i].y - mean) * rstd * g_in[c0 + 1] + b_in[c0 + 1]);
            uv.z = f2bf((xv[i].z - mean) * rstd * g_in[c0 + 2] + b_in[c0 + 2]);
            uv.w = f2bf((xv[i].w - mean) * rstd * g_in[c0 + 3] + b_in[c0 + 3]);
            *(ushort4*)&xA[r][c0] = uv;
        }
    }
    __syncthreads();

    // ---- MFMA: wave w handles coltiles 4w..4w+3 over 2 rowtiles ----
    // waves 0,1 -> K cols 0..127 ; waves 2,3 -> V cols 128..255 (wave-uniform)
    int w = t >> 6, l = t & 63;
    int lc = l & 15, lg = l >> 4;

    bf16x8 bfr[4][4];
    #pragma unroll
    for (int ci = 0; ci < 4; ci++)
        #pragma unroll
        for (int ks = 0; ks < 4; ks++) {
            int ct = w * 4 + ci;
            bfr[ci][ks] = *(const bf16x8*)(WkvF + ((size_t)((ct * 4 + ks) * 64 + l)) * 8);
        }

    f32x4 acc[2][4];
    #pragma unroll
    for (int rt = 0; rt < 2; rt++)
        #pragma unroll
        for (int ci = 0; ci < 4; ci++) acc[rt][ci] = (f32x4){0.f, 0.f, 0.f, 0.f};

    #pragma unroll
    for (int rt = 0; rt < 2; rt++) {
        bf16x8 afr[4];
        #pragma unroll
        for (int ks = 0; ks < 4; ks++)
            afr[ks] = *(const bf16x8*)&xA[rt * 16 + lc][ks * 32 + lg * 8];
        #pragma unroll
        for (int ci = 0; ci < 4; ci++)
            #pragma unroll
            for (int ks = 0; ks < 4; ks++)
                acc[rt][ci] = __builtin_amdgcn_mfma_f32_16x16x32_bf16(
                    afr[ks], bfr[ci][ks], acc[rt][ci], 0, 0, 0);
    }

    // ---- epilogue: bias add, stage to LDS; V also accumulates svp ----
    float svpart[4] = {0.f, 0.f, 0.f, 0.f};
    #pragma unroll
    for (int rt = 0; rt < 2; rt++) {
        #pragma unroll
        for (int ci = 0; ci < 4; ci++) {
            int ct  = w * 4 + ci;
            int col = ct * 16 + lc;                 // 0..255
            float bias = (col < DD) ? bk[col] : bv[col - DD];
            int nloc = rt * 16 + lg * 4;
            if (col < DD) {                         // K: row-major stage
                #pragma unroll
                for (int i = 0; i < 4; i++)
                    kstR[nloc + i][col] = f2bf(acc[rt][ci][i] + bias);
            } else {                                // V: transposed stage
                ushort4 v4;
                v4.x = f2bf(acc[rt][ci][0] + bias);
                v4.y = f2bf(acc[rt][ci][1] + bias);
                v4.z = f2bf(acc[rt][ci][2] + bias);
                v4.w = f2bf(acc[rt][ci][3] + bias);
                *(ushort4*)&vstT[col - DD][nloc] = v4;
                svpart[ci] += acc[rt][ci][0] + acc[rt][ci][1] +
                              acc[rt][ci][2] + acc[rt][ci][3];
            }
        }
    }
    if (w >= 2) {   // svp from regs: reduce over lg lanes (n direction)
        #pragma unroll
        for (int ci = 0; ci < 4; ci++) {
            int col = (w * 4 + ci) * 16 + lc - DD;  // 0..127
            float p = svpart[ci] + 8.0f * bv[col];
            p += __shfl_xor(p, 16);
            p += __shfl_xor(p, 32);
            if (lg == 0) svp[((size_t)(b * LNCH + ch)) * DD + col] = p;
        }
    }
    __syncthreads();

    // ---- coalesced writes ----
    {   // kR: thread t -> row r = t>>3, octet o = t&7 (16 cols = 32B)
        int r = t >> 3, o = t & 7;
        const uint4* src = (const uint4*)&kstR[r][o * 16];
        uint4* dst = (uint4*)(kR + ((size_t)(b * NN + n0 + r)) * DD + o * 16);
        dst[0] = src[0];
        dst[1] = src[1];
    }
    {   // vT: thread t -> col c = t>>1, half h = t&1 (16 n = 32B)
        int c = t >> 1, h = t & 1;
        const uint4* src = (const uint4*)&vstT[c][h * 16];
        uint4* dst = (uint4*)(vT + ((size_t)(b * DD + c)) * NN + n0 + h * 16);
        dst[0] = src[0];
        dst[1] = src[1];
    }
}

// ------------------------------------------------------------------
__global__ __launch_bounds__(512) void k_sumv(const float* __restrict__ svp,
                                              float* __restrict__ sumv) {
    int b = blockIdx.x, t = threadIdx.x;
    int c = t & 127, g = t >> 7;        // 4 groups of 128 chunks
    __shared__ float part[4][DD];
    float s = 0.f;
    for (int cb = g * 128; cb < (g + 1) * 128; cb++)
        s += svp[((size_t)(b * LNCH + cb)) * DD + c];
    part[g][c] = s;
    __syncthreads();
    if (t < DD) sumv[b * DD + t] = part[0][t] + part[1][t] + part[2][t] + part[3][t];
}

// ------------------------------------------------------------------
__device__ inline void block_stats(float v, float& mean, float& rstd, float* red) {
    float s = v, sq = v * v;
    #pragma unroll
    for (int o = 32; o > 0; o >>= 1) {
        s  += __shfl_down(s, o, 64);
        sq += __shfl_down(sq, o, 64);
    }
    int lane = threadIdx.x & 63, w = threadIdx.x >> 6;
    if (lane == 0) { red[w * 2] = s; red[w * 2 + 1] = sq; }
    __syncthreads();
    float S = red[0] + red[2], SQ = red[1] + red[3];
    mean = S * (1.0f / DD);
    float var = SQ * (1.0f / DD) - mean * mean;
    rstd = rsqrtf(var + LN_EPS);
    __syncthreads();
}

// ------------------------------------------------------------------
__global__ __launch_bounds__(128) void k_init(
        const float* __restrict__ noise, const float* __restrict__ mu,
        const float* __restrict__ logsigma,
        const float* __restrict__ Wq, const float* __restrict__ bq,
        const float* __restrict__ g_sl, const float* __restrict__ b_sl,
        float* __restrict__ slots, float* __restrict__ q) {
    int bk_ = blockIdx.x;
    int j = threadIdx.x;
    __shared__ float red[4];
    __shared__ float tmp[DD];
    float s = mu[j] + __expf(logsigma[j]) * noise[bk_ * DD + j];
    slots[bk_ * DD + j] = s;
    float m, rs;
    block_stats(s, m, rs, red);
    tmp[j] = (s - m) * rs * g_sl[j] + b_sl[j];
    __syncthreads();
    float qv = bq[j];
    for (int d = 0; d < DD; d++) qv += tmp[d] * Wq[d * DD + j];
    q[bk_ * DD + j] = qv;
}

// ------------------------------------------------------------------
// MFMA attention iteration. 256 threads (4 waves), NB=128 n per block.
// dots^T:   C[n][slot] = K[n][:] . q[slot][:]   (A = K rows, B = q^T)
// softmax over slots per n via 16-lane shfl reduce.
// updates^T: C'[d][slot] = vT[d][:] . P[:][slot] (A = vT rows, B = P)
// P staged [slot][n] so PV B-frags are 16B conflict-free LDS reads.
__global__ __launch_bounds__(256) void k_attn(
        const ushort* __restrict__ kR, const ushort* __restrict__ vT,
        const float* __restrict__ q,
        float* __restrict__ upart, float* __restrict__ dpart,
        float* __restrict__ out_s, int last) {
    __shared__ ushort qlds[16][136];   // q bf16, pre-scaled, rows 10-15 zero
    __shared__ ushort plds[16][136];   // P bf16 [slot][n]
    __shared__ float red[4][16];

    int t = threadIdx.x;
    int blk = blockIdx.x;
    int b  = blk >> 7;
    int ch = blk & (NCH - 1);
    int n0 = ch * NB;
    int w = t >> 6, l = t & 63;
    int lc = l & 15, lg = l >> 4;

    const float scale = 0.08838834764831845f;   // D^-0.5
    for (int j = t; j < 16 * DD; j += 256) {
        int row = j >> 7, col = j & 127;
        float v = (row < KK) ? q[((size_t)b * KK + row) * DD + col] * scale : 0.f;
        qlds[row][col] = f2bf(v);
    }
    __syncthreads();

    // q B-frags: B[k=d][col=slot] -> qlds[lc][ks*32+lg*8+j]
    bf16x8 qb[4];
    #pragma unroll
    for (int ks = 0; ks < 4; ks++)
        qb[ks] = *(const bf16x8*)&qlds[lc][ks * 32 + lg * 8];

    float dsum = 0.f;
    bool valid = lc < KK;
    #pragma unroll
    for (int tt = 0; tt < 2; tt++) {
        int nt = w * 2 + tt;    // n-tile 0..7
        const ushort* kb = kR + ((size_t)(b * NN + n0 + nt * 16 + lc)) * DD + lg * 8;
        f32x4 acc = (f32x4){0.f, 0.f, 0.f, 0.f};
        #pragma unroll
        for (int ks = 0; ks < 4; ks++) {
            bf16x8 a = *(const bf16x8*)(kb + ks * 32);   // 16B coalesced
            acc = __builtin_amdgcn_mfma_f32_16x16x32_bf16(a, qb[ks], acc, 0, 0, 0);
        }
        // softmax per row (n); C layout: row=(l>>4)*4+r, col=slot=lc
        #pragma unroll
        for (int r = 0; r < 4; r++) {
            float v = acc[r];
            float m = valid ? v : -3.0e38f;
            m = fmaxf(m, __shfl_xor(m, 1));
            m = fmaxf(m, __shfl_xor(m, 2));
            m = fmaxf(m, __shfl_xor(m, 4));
            m = fmaxf(m, __shfl_xor(m, 8));
            float e = valid ? __expf(v - m) : 0.f;
            float s = e;
            s += __shfl_xor(s, 1);
            s += __shfl_xor(s, 2);
            s += __shfl_xor(s, 4);
            s += __shfl_xor(s, 8);
            float p = e / s;
            dsum += p;
            plds[lc][nt * 16 + lg * 4 + r] = f2bf(p);
        }
    }
    // denom partial: sum over this wave's 32 n, per slot
    dsum += __shfl_xor(dsum, 16);
    dsum += __shfl_xor(dsum, 32);
    if (l < 16) red[w][l] = dsum;
    __syncthreads();

    if (t < KK)
        dpart[((size_t)b * KK + t) * NCH + ch] =
            red[0][t] + red[1][t] + red[2][t] + red[3][t];

    // P B-frags: B[k=n][col=slot] -> plds[lc][ks*32+lg*8+j]  (16B reads)
    bf16x8 pb[4];
    #pragma unroll
    for (int ks = 0; ks < 4; ks++)
        pb[ks] = *(const bf16x8*)&plds[lc][ks * 32 + lg * 8];

    #pragma unroll
    for (int tt = 0; tt < 2; tt++) {
        int dt = w * 2 + tt;    // d-tile 0..7
        const ushort* vb = vT + ((size_t)(b * DD + dt * 16 + lc)) * NN + n0 + lg * 8;
        f32x4 uacc = (f32x4){0.f, 0.f, 0.f, 0.f};
        #pragma unroll
        for (int ks = 0; ks < 4; ks++) {
            bf16x8 a = *(const bf16x8*)(vb + ks * 32);   // 16B coalesced
            uacc = __builtin_amdgcn_mfma_f32_16x16x32_bf16(a, pb[ks], uacc, 0, 0, 0);
        }
        if (valid) {   // C' row = d local = lg*4+r, col = slot = lc
            float4 st = {uacc[0], uacc[1], uacc[2], uacc[3]};
            *(float4*)&upart[(((size_t)b * KK + lc) * NCH + ch) * DD + dt * 16 + lg * 4] = st;
        }
    }

    if (last) {
        for (int i = t; i < NB * KK; i += 256) {
            int n = i / KK, s2 = i - n * KK;
            out_s[((size_t)b * NN + n0 + n) * KK + s2] = bf2f(plds[s2][n]);
        }
    }
}

// ------------------------------------------------------------------
// Reduce partials -> updates; GRU; LN+MLP residual; next q. 384 threads.
__global__ __launch_bounds__(384) void k_slot(
        const float* __restrict__ upart, const float* __restrict__ dpart,
        const float* __restrict__ sumv,
        const float* __restrict__ WihT, const float* __restrict__ WhhT,
        const float* __restrict__ bih, const float* __restrict__ bhh,
        const float* __restrict__ W1, const float* __restrict__ b1,
        const float* __restrict__ W2, const float* __restrict__ b2,
        const float* __restrict__ Wq, const float* __restrict__ bq,
        const float* __restrict__ g_ff, const float* __restrict__ b_ff,
        const float* __restrict__ g_sl, const float* __restrict__ b_sl,
        float* __restrict__ slots, float* __restrict__ q,
        float* __restrict__ out_nf, float* __restrict__ out_adj, int last) {
    int blk = blockIdx.x;
    int b = blk / KK, kslot = blk % KK;
    int t = threadIdx.x;
    __shared__ float u_lds[DD], p_lds[DD], tmp[DD];
    __shared__ float gi_lds[3 * DD], gh_lds[3 * DD];
    __shared__ float upr[3][DD];
    __shared__ float red[8];

    // --- u partial reduce: dense stream over [NCH][D] slice ---
    {
        int j = t & 127, g = t >> 7;
        int c0 = g * 43, c1 = (g == 2) ? NCH : c0 + 43;
        const float* up = upart + ((size_t)(b * KK + kslot) * NCH) * DD + j;
        float u = 0.f;
        for (int c = c0; c < c1; c++) u += up[(size_t)c * DD];
        upr[g][j] = u;
    }
    // --- denom: dense 512B read + shfl reduce ---
    {
        float dsv = 0.f;
        if (t < 64) {
            const float* dp = dpart + (size_t)(b * KK + kslot) * NCH;
            dsv = dp[2 * t] + dp[2 * t + 1];
        }
        #pragma unroll
        for (int o = 32; o > 0; o >>= 1) dsv += __shfl_xor(dsv, o);
        if (t == 0) red[6] = dsv + (float)NN * ATT_EPS;
    }
    __syncthreads();

    float snew = 0.f, prev = 0.f;
    if (t < DD) {
        float u = upr[0][t] + upr[1][t] + upr[2][t];
        float upd = (u + ATT_EPS * sumv[b * DD + t]) / red[6];
        prev = slots[(b * KK + kslot) * DD + t];
        u_lds[t] = upd;
        p_lds[t] = prev;
    }
    __syncthreads();

    // --- gi/gh: one column per thread (384 columns) ---
    {
        float gi = bih[t], gh = bhh[t];
        for (int d4 = 0; d4 < DD / 4; d4++) {
            float4 uv = *(const float4*)&u_lds[d4 * 4];
            float4 pv = *(const float4*)&p_lds[d4 * 4];
            const float* wi = WihT + (size_t)(d4 * 4) * 3 * DD + t;
            const float* wh = WhhT + (size_t)(d4 * 4) * 3 * DD + t;
            gi += uv.x * wi[0] + uv.y * wi[3 * DD] + uv.z * wi[6 * DD] + uv.w * wi[9 * DD];
            gh += pv.x * wh[0] + pv.y * wh[3 * DD] + pv.z * wh[6 * DD] + pv.w * wh[9 * DD];
        }
        gi_lds[t] = gi;
        gh_lds[t] = gh;
    }
    __syncthreads();

    if (t < DD) {
        float r = 1.f / (1.f + __expf(-(gi_lds[t] + gh_lds[t])));
        float z = 1.f / (1.f + __expf(-(gi_lds[DD + t] + gh_lds[DD + t])));
        float nn_ = tanhf(gi_lds[2 * DD + t] + r * gh_lds[2 * DD + t]);
        snew = (1.f - z) * nn_ + z * prev;
    }
    // --- LN(snew) over 128 active threads ---
    {
        float s_ = (t < DD) ? snew : 0.f, sq_ = s_ * s_;
        #pragma unroll
        for (int o = 32; o > 0; o >>= 1) { s_ += __shfl_xor(s_, o); sq_ += __shfl_xor(sq_, o); }
        if (t < DD && (t & 63) == 0) { red[(t >> 6) * 2] = s_; red[(t >> 6) * 2 + 1] = sq_; }
    }
    __syncthreads();
    if (t < DD) {
        float mean = (red[0] + red[2]) * (1.0f / DD);
        float var  = (red[1] + red[3]) * (1.0f / DD) - mean * mean;
        float rstd = rsqrtf(var + LN_EPS);
        tmp[t] = (snew - mean) * rstd * g_ff[t] + b_ff[t];
    }
    __syncthreads();
    float h = 0.f;
    if (t < DD) {
        h = b1[t];
        for (int d4 = 0; d4 < DD / 4; d4++) {
            float4 tv = *(const float4*)&tmp[d4 * 4];
            const float* wp = W1 + (size_t)(d4 * 4) * DD + t;
            h += tv.x * wp[0] + tv.y * wp[DD] + tv.z * wp[2 * DD] + tv.w * wp[3 * DD];
        }
        h = fmaxf(h, 0.f);
    }
    __syncthreads();
    if (t < DD) tmp[t] = h;
    __syncthreads();
    float o = 0.f;
    if (t < DD) {
        o = snew + b2[t];
        for (int d4 = 0; d4 < DD / 4; d4++) {
            float4 tv = *(const float4*)&tmp[d4 * 4];
            const float* wp = W2 + (size_t)(d4 * 4) * DD + t;
            o += tv.x * wp[0] + tv.y * wp[DD] + tv.z * wp[2 * DD] + tv.w * wp[3 * DD];
        }
        slots[(b * KK + kslot) * DD + t] = o;
    }
    // --- LN(o) + q for next iteration ---
    {
        float s_ = (t < DD) ? o : 0.f, sq_ = s_ * s_;
        #pragma unroll
        for (int o2 = 32; o2 > 0; o2 >>= 1) { s_ += __shfl_xor(s_, o2); sq_ += __shfl_xor(sq_, o2); }
        if (t < DD && (t & 63) == 0) { red[(t >> 6) * 2] = s_; red[(t >> 6) * 2 + 1] = sq_; }
    }
    __syncthreads();
    if (t < DD) {
        float mean = (red[0] + red[2]) * (1.0f / DD);
        float var  = (red[1] + red[3]) * (1.0f / DD) - mean * mean;
        float rstd = rsqrtf(var + LN_EPS);
        tmp[t] = (o - mean) * rstd * g_sl[t] + b_sl[t];
    }
    __syncthreads();
    if (t < DD) {
        float qv = bq[t];
        for (int d4 = 0; d4 < DD / 4; d4++) {
            float4 tv = *(const float4*)&tmp[d4 * 4];
            const float* wp = Wq + (size_t)(d4 * 4) * DD + t;
            qv += tv.x * wp[0] + tv.y * wp[DD] + tv.z * wp[2 * DD] + tv.w * wp[3 * DD];
        }
        q[(b * KK + kslot) * DD + t] = qv;
        if (last) {
            out_nf[(b * KK + kslot) * DD + t] = o;
            if (t < KK) out_adj[(b * KK + kslot) * KK + t] = 1.0f;
        }
    }
}

// ------------------------------------------------------------------
extern "C" void kernel_launch(void* const* d_in, const int* in_sizes, int n_in,
                              void* d_out, int out_size, void* d_ws, size_t ws_size,
                              hipStream_t stream) {
    (void)in_sizes; (void)n_in; (void)out_size; (void)ws_size;
    const float* x        = (const float*)d_in[0];
    const float* noise    = (const float*)d_in[1];
    const float* mu       = (const float*)d_in[2];
    const float* logsigma = (const float*)d_in[3];
    const float* Wq  = (const float*)d_in[4];
    const float* bq  = (const float*)d_in[5];
    const float* Wk  = (const float*)d_in[6];
    const float* bk  = (const float*)d_in[7];
    const float* Wv  = (const float*)d_in[8];
    const float* bv  = (const float*)d_in[9];
    const float* Wih = (const float*)d_in[10];
    const float* Whh = (const float*)d_in[11];
    const float* bih = (const float*)d_in[12];
    const float* bhh = (const float*)d_in[13];
    const float* W1  = (const float*)d_in[14];
    const float* b1  = (const float*)d_in[15];
    const float* W2  = (const float*)d_in[16];
    const float* b2  = (const float*)d_in[17];
    const float* g_in = (const float*)d_in[18];
    const float* b_in = (const float*)d_in[19];
    const float* g_sl = (const float*)d_in[20];
    const float* b_sl = (const float*)d_in[21];
    const float* g_ff = (const float*)d_in[22];
    const float* b_ff = (const float*)d_in[23];

    float* w = (float*)d_ws;
    ushort* kR   = (ushort*)(w + OFF_KR);
    ushort* vT   = (ushort*)(w + OFF_VT);
    ushort* WkvF = (ushort*)(w + OFF_WKVF);
    float* qbuf  = w + OFF_Q;
    float* slots = w + OFF_SLOTS;
    float* upart = w + OFF_UPART;
    float* dpart = w + OFF_DPART;
    float* svp   = w + OFF_SVP;
    float* sumv  = w + OFF_SUMV;
    float* WihT  = w + OFF_WIHT;
    float* WhhT  = w + OFF_WHHT;

    float* out_nf  = (float*)d_out;                       // [B,K,D]
    float* out_adj = out_nf + BB * KK * DD;               // [B,K,K]
    float* out_s   = out_adj + BB * KK * KK;              // [B,N,K]

    k_prep<<<320, 256, 0, stream>>>(Wih, Whh, Wk, Wv, WihT, WhhT, WkvF);
    k_ln_kv<<<BB * LNCH, 256, 0, stream>>>(x, WkvF, bk, bv, g_in, b_in,
                                           kR, vT, svp);
    k_sumv<<<BB, 512, 0, stream>>>(svp, sumv);
    k_init<<<BB * KK, 128, 0, stream>>>(noise, mu, logsigma, Wq, bq, g_sl, b_sl,
                                        slots, qbuf);

    for (int it = 0; it < N_ITERS; it++) {
        int last = (it == N_ITERS - 1) ? 1 : 0;
        k_attn<<<BB * NCH, 256, 0, stream>>>(kR, vT, qbuf, upart, dpart, out_s, last);
        k_slot<<<BB * KK, 384, 0, stream>>>(upart, dpart, sumv, WihT, WhhT,
                                            bih, bhh, W1, b1, W2, b2, Wq, bq,
                                            g_ff, b_ff, g_sl, b_sl,
                                            slots, qbuf, out_nf, out_adj, last);
    }
}

// Round 8
// 334.215 us; speedup vs baseline: 1.0780x; 1.0780x over previous
//
#include <hip/hip_runtime.h>
#include <cstdint>

#define BB 8
#define NN 16384
#define DD 128
#define KK 10
#define N_ITERS 7
#define LN_EPS 1e-5f
#define ATT_EPS 1e-8f
#define SCALE 0.08838834764831845f   // D^-0.5

#define LNR 64                 // rows per ln block
#define LNCH (NN / LNR)        // 256 chunks per batch
#define NB 128                 // n per attn block
#define NCH (NN / NB)          // 128 chunks per batch

typedef __attribute__((ext_vector_type(8))) short bf16x8;
typedef __attribute__((ext_vector_type(4))) float f32x4;

__device__ inline ushort f2bf(float f) {
    uint u = __builtin_bit_cast(uint, f);
    u += 0x7FFFu + ((u >> 16) & 1u);
    return (ushort)(u >> 16);
}
__device__ inline float bf2f(ushort u) {
    return __builtin_bit_cast(float, ((uint)u) << 16);
}

// ---- workspace layout (float units; bf16 arrays use 2 per float) ----
// xn: LN(x) row-major [B][N][D] bf16 ; xnT: transposed [B][D][N] bf16
// upart: [B][NCH][K][D] (r6 layout) ; dpart: [B][NCH][K]
#define OFF_XN    ((size_t)0)
#define OFF_XNT   (OFF_XN + (size_t)BB * NN * DD / 2)
#define OFF_WKT   (OFF_XNT + (size_t)BB * NN * DD / 2)
#define OFF_Q     (OFF_WKT + (size_t)DD * DD)
#define OFF_QC0   (OFF_Q + (size_t)BB * KK * DD)
#define OFF_SLOTS (OFF_QC0 + 128)
#define OFF_UPART (OFF_SLOTS + (size_t)BB * KK * DD)
#define OFF_DPART (OFF_UPART + (size_t)BB * NCH * KK * DD)
#define OFF_SXP   (OFF_DPART + (size_t)BB * NCH * KK)
#define OFF_SUMX  (OFF_SXP + (size_t)BB * LNCH * DD)
#define OFF_WIHT  (OFF_SUMX + (size_t)BB * DD)
#define OFF_WHHT  (OFF_WIHT + (size_t)3 * DD * DD)

// ------------------------------------------------------------------
// Prep: WihT/WhhT transposes + WkT transpose (all fp32).
__global__ void k_prep(const float* __restrict__ Wih, const float* __restrict__ Whh,
                       const float* __restrict__ Wk,
                       float* __restrict__ WihT, float* __restrict__ WhhT,
                       float* __restrict__ WkT) {
    int idx = blockIdx.x * 256 + threadIdx.x;
    if (idx < 3 * DD * DD) {
        int d = idx / (3 * DD);
        int j = idx % (3 * DD);
        WihT[idx] = Wih[j * DD + d];
        WhhT[idx] = Whh[j * DD + d];
    } else if (idx < 3 * DD * DD + DD * DD) {
        int i = idx - 3 * DD * DD;
        int d = i / DD, e = i % DD;     // WkT[d][e] = Wk[e][d]
        WkT[i] = Wk[e * DD + d];
    }
}

// ------------------------------------------------------------------
// Pure LayerNorm: x -> xn (row-major bf16) + xnT (transposed bf16) +
// sxp (partial column sums of xn). Memory-bound; no MFMA, no weights.
__global__ __launch_bounds__(256) void k_ln(
        const float* __restrict__ x,
        const float* __restrict__ g_in, const float* __restrict__ b_in,
        ushort* __restrict__ xn, ushort* __restrict__ xnT,
        float* __restrict__ sxp) {
    __shared__ ushort xt[LNR][136];   // 17.4 KB -> 9 blocks/CU

    int t = threadIdx.x, blk = blockIdx.x;
    int b = blk >> 8, ch = blk & (LNCH - 1);
    int n0 = ch * LNR;

    // ---- LN: thread (r = t>>2, p = t&3) owns 32 cols of row r ----
    {
        int r = t >> 2, p = t & 3;
        const float4* xr = (const float4*)(x + ((size_t)(b * NN + n0 + r)) * DD + p * 32);
        float4 xv[8];
        float s = 0.f, sq = 0.f;
        #pragma unroll
        for (int i = 0; i < 8; i++) {
            xv[i] = xr[i];
            s  += xv[i].x + xv[i].y + xv[i].z + xv[i].w;
            sq += xv[i].x * xv[i].x + xv[i].y * xv[i].y +
                  xv[i].z * xv[i].z + xv[i].w * xv[i].w;
        }
        s += __shfl_xor(s, 1);  sq += __shfl_xor(sq, 1);
        s += __shfl_xor(s, 2);  sq += __shfl_xor(sq, 2);
        float mean = s * (1.0f / DD);
        float var  = sq * (1.0f / DD) - mean * mean;
        float rstd = rsqrtf(var + LN_EPS);
        ushort* xno = xn + ((size_t)(b * NN + n0 + r)) * DD + p * 32;
        #pragma unroll
        for (int i = 0; i < 8; i++) {
            int c0 = p * 32 + i * 4;
            ushort4 uv;
            uv.x = f2bf((xv[i].x - mean) * rstd * g_in[c0 + 0] + b_in[c0 + 0]);
            uv.y = f2bf((xv[i].y - mean) * rstd * g_in[c0 + 1] + b_in[c0 + 1]);
            uv.z = f2bf((xv[i].z - mean) * rstd * g_in[c0 + 2] + b_in[c0 + 2]);
            uv.w = f2bf((xv[i].w - mean) * rstd * g_in[c0 + 3] + b_in[c0 + 3]);
            *(ushort4*)&xt[r][c0] = uv;
            *(ushort4*)(xno + i * 4) = uv;        // coalesced row write
        }
    }
    __syncthreads();

    // ---- transposed write + column-sum partials ----
    {
        int c = t >> 1, h = t & 1;      // col 0..127, half 0/1 (32 n each)
        float sx = 0.f;
        ushort vals[32];
        #pragma unroll
        for (int rr = 0; rr < 32; rr++) {
            ushort u = xt[h * 32 + rr][c];
            vals[rr] = u;
            sx += bf2f(u);
        }
        ushort* xto = xnT + ((size_t)(b * DD + c)) * NN + n0 + h * 32;
        #pragma unroll
        for (int i = 0; i < 8; i++) {
            ushort4 o;
            o.x = vals[4 * i + 0]; o.y = vals[4 * i + 1];
            o.z = vals[4 * i + 2]; o.w = vals[4 * i + 3];
            *(ushort4*)(xto + i * 4) = o;
        }
        sx += __shfl_xor(sx, 1);        // combine the two halves of col c
        if (h == 0) sxp[((size_t)(b * LNCH + ch)) * DD + c] = sx;
    }
}

// ------------------------------------------------------------------
__global__ __launch_bounds__(512) void k_sumx(const float* __restrict__ sxp,
                                              float* __restrict__ sumx) {
    int b = blockIdx.x, t = threadIdx.x;
    int c = t & 127, g = t >> 7;        // 4 groups of 64 chunks
    __shared__ float part[4][DD];
    float s = 0.f;
    for (int cb = g * 64; cb < (g + 1) * 64; cb++)
        s += sxp[((size_t)(b * LNCH + cb)) * DD + c];
    part[g][c] = s;
    __syncthreads();
    if (t < DD) sumx[b * DD + t] = part[0][t] + part[1][t] + part[2][t] + part[3][t];
}

// ------------------------------------------------------------------
__device__ inline void block_stats(float v, float& mean, float& rstd, float* red) {
    float s = v, sq = v * v;
    #pragma unroll
    for (int o = 32; o > 0; o >>= 1) {
        s  += __shfl_down(s, o, 64);
        sq += __shfl_down(sq, o, 64);
    }
    int lane = threadIdx.x & 63, w = threadIdx.x >> 6;
    if (lane == 0) { red[w * 2] = s; red[w * 2 + 1] = sq; }
    __syncthreads();
    float S = red[0] + red[2], SQ = red[1] + red[3];
    mean = S * (1.0f / DD);
    float var = SQ * (1.0f / DD) - mean * mean;
    rstd = rsqrtf(var + LN_EPS);
    __syncthreads();
}

// ------------------------------------------------------------------
// slots init; q = LN(slots)@Wq + bq; qp = SCALE*(q@WkT); qc0 = SCALE*(q.bk)
__global__ __launch_bounds__(128) void k_init(
        const float* __restrict__ noise, const float* __restrict__ mu,
        const float* __restrict__ logsigma,
        const float* __restrict__ Wq, const float* __restrict__ bq,
        const float* __restrict__ WkT, const float* __restrict__ bk,
        const float* __restrict__ g_sl, const float* __restrict__ b_sl,
        float* __restrict__ slots, float* __restrict__ qp,
        float* __restrict__ qc0) {
    int bk_ = blockIdx.x;
    int j = threadIdx.x;
    __shared__ float red[4];
    __shared__ float tmp[DD], q_l[DD];
    float s = mu[j] + __expf(logsigma[j]) * noise[bk_ * DD + j];
    slots[bk_ * DD + j] = s;
    float m, rs;
    block_stats(s, m, rs, red);
    tmp[j] = (s - m) * rs * g_sl[j] + b_sl[j];
    __syncthreads();
    float qv = bq[j];
    for (int d = 0; d < DD; d++) qv += tmp[d] * Wq[d * DD + j];
    q_l[j] = qv;
    __syncthreads();
    float qq = 0.f;
    for (int d = 0; d < DD; d++) qq += q_l[d] * WkT[d * DD + j];
    qp[bk_ * DD + j] = SCALE * qq;
    float cp = q_l[j] * bk[j];
    #pragma unroll
    for (int o = 32; o > 0; o >>= 1) cp += __shfl_xor(cp, o);
    if ((j & 63) == 0) red[j >> 6] = cp;
    __syncthreads();
    if (j == 0) qc0[bk_] = SCALE * (red[0] + red[1]);
}

// ------------------------------------------------------------------
// MFMA attention iteration — byte-identical structure to the measured
// 315us r6 kernel, with kR->xn, vT->xnT, q->qp (scale-folded) + c0 bias.
// dots^T:  C[n][slot] = xn[n][:] . qp[slot][:] + c0[slot]
// updates: C'[d][slot] = xnT[d][:] . P[:][slot]   (P = attn, bf16 LDS)
__global__ __launch_bounds__(256) void k_attn(
        const ushort* __restrict__ xn, const ushort* __restrict__ xnT,
        const float* __restrict__ qp, const float* __restrict__ qc0,
        float* __restrict__ upart, float* __restrict__ dpart,
        float* __restrict__ out_s, int last) {
    __shared__ ushort qlds[16][136];   // qp bf16, rows 10-15 zero
    __shared__ ushort plds[NB][18];    // P bf16 [n][slot], pad 18
    __shared__ float red2[4][16];
    __shared__ float c0s[16];

    int t = threadIdx.x;
    int blk = blockIdx.x;
    int b  = blk >> 7;
    int ch = blk & (NCH - 1);
    int n0 = ch * NB;
    int w = t >> 6, l = t & 63;
    int lc = l & 15, lg = l >> 4;

    for (int j = t; j < 16 * DD; j += 256) {
        int row = j >> 7, col = j & 127;
        float v = (row < KK) ? qp[((size_t)b * KK + row) * DD + col] : 0.f;
        qlds[row][col] = f2bf(v);
    }
    if (t < 16) c0s[t] = (t < KK) ? qc0[b * KK + t] : 0.f;
    __syncthreads();

    // qp B-frags: B[k=d][col=slot] -> qlds[lc][ks*32+lg*8+j]
    bf16x8 qb[4];
    #pragma unroll
    for (int ks = 0; ks < 4; ks++)
        qb[ks] = *(const bf16x8*)&qlds[lc][ks * 32 + lg * 8];
    float c0v = c0s[lc];

    float dsum = 0.f;
    bool valid = lc < KK;
    #pragma unroll
    for (int tt = 0; tt < 2; tt++) {
        int nt = w * 2 + tt;    // n-tile 0..7
        const ushort* kb = xn + ((size_t)(b * NN + n0 + nt * 16 + lc)) * DD + lg * 8;
        f32x4 acc = (f32x4){0.f, 0.f, 0.f, 0.f};
        #pragma unroll
        for (int ks = 0; ks < 4; ks++) {
            bf16x8 a = *(const bf16x8*)(kb + ks * 32);   // 16B coalesced
            acc = __builtin_amdgcn_mfma_f32_16x16x32_bf16(a, qb[ks], acc, 0, 0, 0);
        }
        // softmax per row (n); C layout: row=(l>>4)*4+r, col=slot=lc
        #pragma unroll
        for (int r = 0; r < 4; r++) {
            float v = acc[r] + c0v;
            float m = valid ? v : -3.0e38f;
            m = fmaxf(m, __shfl_xor(m, 1));
            m = fmaxf(m, __shfl_xor(m, 2));
            m = fmaxf(m, __shfl_xor(m, 4));
            m = fmaxf(m, __shfl_xor(m, 8));
            float e = valid ? __expf(v - m) : 0.f;
            float s = e;
            s += __shfl_xor(s, 1);
            s += __shfl_xor(s, 2);
            s += __shfl_xor(s, 4);
            s += __shfl_xor(s, 8);
            float p = e / s;
            dsum += p;
            plds[nt * 16 + lg * 4 + r][lc] = f2bf(p);
        }
    }
    // denom partial: sum over this wave's 32 n, per slot
    dsum += __shfl_xor(dsum, 16);
    dsum += __shfl_xor(dsum, 32);
    if (l < 16) red2[w][l] = dsum;
    __syncthreads();

    if (t < KK)
        dpart[((size_t)b * NCH + ch) * KK + t] =
            red2[0][t] + red2[1][t] + red2[2][t] + red2[3][t];

    // P B-frags: B[k=n][col=slot] -> plds[ks*32+lg*8+j][lc]
    bf16x8 pb[4];
    #pragma unroll
    for (int ks = 0; ks < 4; ks++) {
        #pragma unroll
        for (int j = 0; j < 8; j++)
            pb[ks][j] = (short)plds[ks * 32 + lg * 8 + j][lc];
    }

    float* ud = upart + ((size_t)b * NCH + ch) * KK * DD;
    #pragma unroll
    for (int tt = 0; tt < 2; tt++) {
        int dt = w * 2 + tt;    // d-tile 0..7
        const ushort* vb = xnT + ((size_t)(b * DD + dt * 16 + lc)) * NN + n0 + lg * 8;
        f32x4 uacc = (f32x4){0.f, 0.f, 0.f, 0.f};
        #pragma unroll
        for (int ks = 0; ks < 4; ks++) {
            bf16x8 a = *(const bf16x8*)(vb + ks * 32);   // 16B coalesced
            uacc = __builtin_amdgcn_mfma_f32_16x16x32_bf16(a, pb[ks], uacc, 0, 0, 0);
        }
        if (valid) {   // C' row = d local = lg*4+r, col = slot = lc
            float4 st = {uacc[0], uacc[1], uacc[2], uacc[3]};
            *(float4*)&ud[lc * DD + dt * 16 + lg * 4] = st;
        }
    }

    if (last) {
        for (int i = t; i < NB * KK; i += 256) {
            int n = i / KK, s2 = i - n * KK;
            out_s[((size_t)b * NN + n0 + n) * KK + s2] = bf2f(plds[n][s2]);
        }
    }
}

// ------------------------------------------------------------------
// Reduce partials -> Yw; updates = Yw@Wv + bv; GRU; LN+MLP; next qp/qc0.
__global__ __launch_bounds__(384) void k_slot(
        const float* __restrict__ upart, const float* __restrict__ dpart,
        const float* __restrict__ sumx,
        const float* __restrict__ Wv, const float* __restrict__ bv,
        const float* __restrict__ WihT, const float* __restrict__ WhhT,
        const float* __restrict__ bih, const float* __restrict__ bhh,
        const float* __restrict__ W1, const float* __restrict__ b1,
        const float* __restrict__ W2, const float* __restrict__ b2,
        const float* __restrict__ Wq, const float* __restrict__ bq,
        const float* __restrict__ WkT, const float* __restrict__ bk,
        const float* __restrict__ g_ff, const float* __restrict__ b_ff,
        const float* __restrict__ g_sl, const float* __restrict__ b_sl,
        float* __restrict__ slots, float* __restrict__ qp,
        float* __restrict__ qc0,
        float* __restrict__ out_nf, float* __restrict__ out_adj, int last) {
    int blk = blockIdx.x;
    int b = blk / KK, kslot = blk % KK;
    int t = threadIdx.x;
    __shared__ float u_lds[DD], p_lds[DD], tmp[DD], y_lds[DD], q_l[DD];
    __shared__ float gi_lds[3 * DD], gh_lds[3 * DD];
    __shared__ float upr[3][DD];
    __shared__ float red[8];

    // --- u partial reduce (r6 pattern: strided over 128 chunks) ---
    {
        int j = t & 127, g = t >> 7;
        int c0 = g * 43, c1 = (g == 2) ? NCH : c0 + 43;
        float u = 0.f;
        const float* up = upart + (size_t)b * NCH * KK * DD + kslot * DD + j;
        for (int c = c0; c < c1; c++) u += up[(size_t)c * KK * DD];
        upr[g][j] = u;
    }
    // --- denom: 64 threads, 2 chunks each, shfl reduce ---
    {
        float dsv = 0.f;
        if (t < 64) {
            const float* dp = dpart + (size_t)b * NCH * KK + kslot;
            dsv = dp[(size_t)(2 * t) * KK] + dp[(size_t)(2 * t + 1) * KK];
        }
        #pragma unroll
        for (int o = 32; o > 0; o >>= 1) dsv += __shfl_xor(dsv, o);
        if (t == 0) red[6] = dsv + (float)NN * ATT_EPS;
    }
    __syncthreads();

    float prev = 0.f;
    if (t < DD) {
        float u = upr[0][t] + upr[1][t] + upr[2][t];
        y_lds[t] = (u + ATT_EPS * sumx[b * DD + t]) / red[6];   // Yw
        prev = slots[(b * KK + kslot) * DD + t];
        p_lds[t] = prev;
    }
    __syncthreads();

    // --- updates = Yw @ Wv + bv (folded V projection) ---
    if (t < DD) {
        float upd = bv[t];
        for (int d4 = 0; d4 < DD / 4; d4++) {
            float4 yv = *(const float4*)&y_lds[d4 * 4];
            const float* wp = Wv + (size_t)(d4 * 4) * DD + t;
            upd += yv.x * wp[0] + yv.y * wp[DD] + yv.z * wp[2 * DD] + yv.w * wp[3 * DD];
        }
        u_lds[t] = upd;
    }
    __syncthreads();

    // --- gi/gh: one column per thread (384 columns) ---
    {
        float gi = bih[t], gh = bhh[t];
        for (int d4 = 0; d4 < DD / 4; d4++) {
            float4 uv = *(const float4*)&u_lds[d4 * 4];
            float4 pv = *(const float4*)&p_lds[d4 * 4];
            const float* wi = WihT + (size_t)(d4 * 4) * 3 * DD + t;
            const float* wh = WhhT + (size_t)(d4 * 4) * 3 * DD + t;
            gi += uv.x * wi[0] + uv.y * wi[3 * DD] + uv.z * wi[6 * DD] + uv.w * wi[9 * DD];
            gh += pv.x * wh[0] + pv.y * wh[3 * DD] + pv.z * wh[6 * DD] + pv.w * wh[9 * DD];
        }
        gi_lds[t] = gi;
        gh_lds[t] = gh;
    }
    __syncthreads();

    float snew = 0.f;
    if (t < DD) {
        float r = 1.f / (1.f + __expf(-(gi_lds[t] + gh_lds[t])));
        float z = 1.f / (1.f + __expf(-(gi_lds[DD + t] + gh_lds[DD + t])));
        float nn_ = tanhf(gi_lds[2 * DD + t] + r * gh_lds[2 * DD + t]);
        snew = (1.f - z) * nn_ + z * prev;
    }
    // --- LN(snew) ---
    {
        float s_ = (t < DD) ? snew : 0.f, sq_ = s_ * s_;
        #pragma unroll
        for (int o = 32; o > 0; o >>= 1) { s_ += __shfl_xor(s_, o); sq_ += __shfl_xor(sq_, o); }
        if (t < DD && (t & 63) == 0) { red[(t >> 6) * 2] = s_; red[(t >> 6) * 2 + 1] = sq_; }
    }
    __syncthreads();
    if (t < DD) {
        float mean = (red[0] + red[2]) * (1.0f / DD);
        float var  = (red[1] + red[3]) * (1.0f / DD) - mean * mean;
        float rstd = rsqrtf(var + LN_EPS);
        tmp[t] = (snew - mean) * rstd * g_ff[t] + b_ff[t];
    }
    __syncthreads();
    float h = 0.f;
    if (t < DD) {
        h = b1[t];
        for (int d4 = 0; d4 < DD / 4; d4++) {
            float4 tv = *(const float4*)&tmp[d4 * 4];
            const float* wp = W1 + (size_t)(d4 * 4) * DD + t;
            h += tv.x * wp[0] + tv.y * wp[DD] + tv.z * wp[2 * DD] + tv.w * wp[3 * DD];
        }
        h = fmaxf(h, 0.f);
    }
    __syncthreads();
    if (t < DD) tmp[t] = h;
    __syncthreads();
    float o = 0.f;
    if (t < DD) {
        o = snew + b2[t];
        for (int d4 = 0; d4 < DD / 4; d4++) {
            float4 tv = *(const float4*)&tmp[d4 * 4];
            const float* wp = W2 + (size_t)(d4 * 4) * DD + t;
            o += tv.x * wp[0] + tv.y * wp[DD] + tv.z * wp[2 * DD] + tv.w * wp[3 * DD];
        }
        slots[(b * KK + kslot) * DD + t] = o;
    }
    // --- LN(o) -> q -> qp/qc0 for next iteration ---
    {
        float s_ = (t < DD) ? o : 0.f, sq_ = s_ * s_;
        #pragma unroll
        for (int o2 = 32; o2 > 0; o2 >>= 1) { s_ += __shfl_xor(s_, o2); sq_ += __shfl_xor(sq_, o2); }
        if (t < DD && (t & 63) == 0) { red[(t >> 6) * 2] = s_; red[(t >> 6) * 2 + 1] = sq_; }
    }
    __syncthreads();
    if (t < DD) {
        float mean = (red[0] + red[2]) * (1.0f / DD);
        float var  = (red[1] + red[3]) * (1.0f / DD) - mean * mean;
        float rstd = rsqrtf(var + LN_EPS);
        tmp[t] = (o - mean) * rstd * g_sl[t] + b_sl[t];
    }
    __syncthreads();
    if (t < DD) {
        float qv = bq[t];
        for (int d4 = 0; d4 < DD / 4; d4++) {
            float4 tv = *(const float4*)&tmp[d4 * 4];
            const float* wp = Wq + (size_t)(d4 * 4) * DD + t;
            qv += tv.x * wp[0] + tv.y * wp[DD] + tv.z * wp[2 * DD] + tv.w * wp[3 * DD];
        }
        q_l[t] = qv;
    }
    __syncthreads();
    if (t < DD) {
        float qq = 0.f;
        for (int d4 = 0; d4 < DD / 4; d4++) {
            float4 tv = *(const float4*)&q_l[d4 * 4];
            const float* wp = WkT + (size_t)(d4 * 4) * DD + t;
            qq += tv.x * wp[0] + tv.y * wp[DD] + tv.z * wp[2 * DD] + tv.w * wp[3 * DD];
        }
        qp[(b * KK + kslot) * DD + t] = SCALE * qq;
        if (last) {
            out_nf[(b * KK + kslot) * DD + t] = o;
            if (t < KK) out_adj[(b * KK + kslot) * KK + t] = 1.0f;
        }
    }
    {
        float cp = (t < DD) ? q_l[t] * bk[t] : 0.f;
        #pragma unroll
        for (int o2 = 32; o2 > 0; o2 >>= 1) cp += __shfl_xor(cp, o2);
        if (t < 128 && (t & 63) == 0) red[4 + (t >> 6)] = cp;
    }
    __syncthreads();
    if (t == 0) qc0[b * KK + kslot] = SCALE * (red[4] + red[5]);
}

// ------------------------------------------------------------------
extern "C" void kernel_launch(void* const* d_in, const int* in_sizes, int n_in,
                              void* d_out, int out_size, void* d_ws, size_t ws_size,
                              hipStream_t stream) {
    (void)in_sizes; (void)n_in; (void)out_size; (void)ws_size;
    const float* x        = (const float*)d_in[0];
    const float* noise    = (const float*)d_in[1];
    const float* mu       = (const float*)d_in[2];
    const float* logsigma = (const float*)d_in[3];
    const float* Wq  = (const float*)d_in[4];
    const float* bq  = (const float*)d_in[5];
    const float* Wk  = (const float*)d_in[6];
    const float* bk  = (const float*)d_in[7];
    const float* Wv  = (const float*)d_in[8];
    const float* bv  = (const float*)d_in[9];
    const float* Wih = (const float*)d_in[10];
    const float* Whh = (const float*)d_in[11];
    const float* bih = (const float*)d_in[12];
    const float* bhh = (const float*)d_in[13];
    const float* W1  = (const float*)d_in[14];
    const float* b1  = (const float*)d_in[15];
    const float* W2  = (const float*)d_in[16];
    const float* b2  = (const float*)d_in[17];
    const float* g_in = (const float*)d_in[18];
    const float* b_in = (const float*)d_in[19];
    const float* g_sl = (const float*)d_in[20];
    const float* b_sl = (const float*)d_in[21];
    const float* g_ff = (const float*)d_in[22];
    const float* b_ff = (const float*)d_in[23];

    float* w = (float*)d_ws;
    ushort* xn   = (ushort*)(w + OFF_XN);
    ushort* xnT  = (ushort*)(w + OFF_XNT);
    float* WkT   = w + OFF_WKT;
    float* qp    = w + OFF_Q;
    float* qc0   = w + OFF_QC0;
    float* slots = w + OFF_SLOTS;
    float* upart = w + OFF_UPART;
    float* dpart = w + OFF_DPART;
    float* sxp   = w + OFF_SXP;
    float* sumx  = w + OFF_SUMX;
    float* WihT  = w + OFF_WIHT;
    float* WhhT  = w + OFF_WHHT;

    float* out_nf  = (float*)d_out;                       // [B,K,D]
    float* out_adj = out_nf + BB * KK * DD;               // [B,K,K]
    float* out_s   = out_adj + BB * KK * KK;              // [B,N,K]

    k_prep<<<256, 256, 0, stream>>>(Wih, Whh, Wk, WihT, WhhT, WkT);
    k_ln<<<BB * LNCH, 256, 0, stream>>>(x, g_in, b_in, xn, xnT, sxp);
    k_sumx<<<BB, 512, 0, stream>>>(sxp, sumx);
    k_init<<<BB * KK, 128, 0, stream>>>(noise, mu, logsigma, Wq, bq, WkT, bk,
                                        g_sl, b_sl, slots, qp, qc0);

    for (int it = 0; it < N_ITERS; it++) {
        int last = (it == N_ITERS - 1) ? 1 : 0;
        k_attn<<<BB * NCH, 256, 0, stream>>>(xn, xnT, qp, qc0, upart, dpart,
                                             out_s, last);
        k_slot<<<BB * KK, 384, 0, stream>>>(upart, dpart, sumx, Wv, bv,
                                            WihT, WhhT, bih, bhh, W1, b1, W2, b2,
                                            Wq, bq, WkT, bk, g_ff, b_ff, g_sl, b_sl,
                                            slots, qp, qc0, out_nf, out_adj, last);
    }
}

// Round 9
// 321.717 us; speedup vs baseline: 1.1198x; 1.0388x over previous
//
#include <hip/hip_runtime.h>
#include <cstdint>

#define BB 8
#define NN 16384
#define DD 128
#define KK 10
#define N_ITERS 7
#define LN_EPS 1e-5f
#define ATT_EPS 1e-8f
#define SCALE 0.08838834764831845f   // D^-0.5

#define LNR 64                 // rows per ln block
#define LNCH (NN / LNR)        // 256 chunks per batch
#define NB 128                 // n per attn block
#define NCH (NN / NB)          // 128 chunks per batch

typedef __attribute__((ext_vector_type(8))) short bf16x8;
typedef __attribute__((ext_vector_type(4))) float f32x4;

__device__ inline ushort f2bf(float f) {
    uint u = __builtin_bit_cast(uint, f);
    u += 0x7FFFu + ((u >> 16) & 1u);
    return (ushort)(u >> 16);
}
__device__ inline float bf2f(ushort u) {
    return __builtin_bit_cast(float, ((uint)u) << 16);
}

// ---- workspace layout (float units; bf16 arrays use 2 per float) ----
// xn: LN(x) row-major [B][N][D] bf16 (the ONLY N-sized tensor)
// upart: [B][NCH][K][D] ; dpart: [B][NCH][K]
#define OFF_XN    ((size_t)0)
#define OFF_WKT   (OFF_XN + (size_t)BB * NN * DD / 2)
#define OFF_Q     (OFF_WKT + (size_t)DD * DD)
#define OFF_QC0   (OFF_Q + (size_t)BB * KK * DD)
#define OFF_SLOTS (OFF_QC0 + 128)
#define OFF_UPART (OFF_SLOTS + (size_t)BB * KK * DD)
#define OFF_DPART (OFF_UPART + (size_t)BB * NCH * KK * DD)
#define OFF_SXP   (OFF_DPART + (size_t)BB * NCH * KK)
#define OFF_SUMX  (OFF_SXP + (size_t)BB * LNCH * DD)
#define OFF_WIHT  (OFF_SUMX + (size_t)BB * DD)
#define OFF_WHHT  (OFF_WIHT + (size_t)3 * DD * DD)

// ------------------------------------------------------------------
// Prep: WihT/WhhT transposes + WkT transpose (all fp32).
__global__ void k_prep(const float* __restrict__ Wih, const float* __restrict__ Whh,
                       const float* __restrict__ Wk,
                       float* __restrict__ WihT, float* __restrict__ WhhT,
                       float* __restrict__ WkT) {
    int idx = blockIdx.x * 256 + threadIdx.x;
    if (idx < 3 * DD * DD) {
        int d = idx / (3 * DD);
        int j = idx % (3 * DD);
        WihT[idx] = Wih[j * DD + d];
        WhhT[idx] = Whh[j * DD + d];
    } else if (idx < 3 * DD * DD + DD * DD) {
        int i = idx - 3 * DD * DD;
        int d = i / DD, e = i % DD;     // WkT[d][e] = Wk[e][d]
        WkT[i] = Wk[e * DD + d];
    }
}

// ------------------------------------------------------------------
// Pure LayerNorm: x -> xn (row-major bf16) + sxp (partial column sums).
__global__ __launch_bounds__(256) void k_ln(
        const float* __restrict__ x,
        const float* __restrict__ g_in, const float* __restrict__ b_in,
        ushort* __restrict__ xn, float* __restrict__ sxp) {
    __shared__ ushort xt[LNR][136];   // 17.4 KB

    int t = threadIdx.x, blk = blockIdx.x;
    int b = blk >> 8, ch = blk & (LNCH - 1);
    int n0 = ch * LNR;

    // ---- LN: thread (r = t>>2, p = t&3) owns 32 cols of row r ----
    {
        int r = t >> 2, p = t & 3;
        const float4* xr = (const float4*)(x + ((size_t)(b * NN + n0 + r)) * DD + p * 32);
        float4 xv[8];
        float s = 0.f, sq = 0.f;
        #pragma unroll
        for (int i = 0; i < 8; i++) {
            xv[i] = xr[i];
            s  += xv[i].x + xv[i].y + xv[i].z + xv[i].w;
            sq += xv[i].x * xv[i].x + xv[i].y * xv[i].y +
                  xv[i].z * xv[i].z + xv[i].w * xv[i].w;
        }
        s += __shfl_xor(s, 1);  sq += __shfl_xor(sq, 1);
        s += __shfl_xor(s, 2);  sq += __shfl_xor(sq, 2);
        float mean = s * (1.0f / DD);
        float var  = sq * (1.0f / DD) - mean * mean;
        float rstd = rsqrtf(var + LN_EPS);
        ushort* xno = xn + ((size_t)(b * NN + n0 + r)) * DD + p * 32;
        #pragma unroll
        for (int i = 0; i < 8; i++) {
            int c0 = p * 32 + i * 4;
            ushort4 uv;
            uv.x = f2bf((xv[i].x - mean) * rstd * g_in[c0 + 0] + b_in[c0 + 0]);
            uv.y = f2bf((xv[i].y - mean) * rstd * g_in[c0 + 1] + b_in[c0 + 1]);
            uv.z = f2bf((xv[i].z - mean) * rstd * g_in[c0 + 2] + b_in[c0 + 2]);
            uv.w = f2bf((xv[i].w - mean) * rstd * g_in[c0 + 3] + b_in[c0 + 3]);
            *(ushort4*)&xt[r][c0] = uv;
            *(ushort4*)(xno + i * 4) = uv;        // coalesced row write
        }
    }
    __syncthreads();

    // ---- column-sum partials ----
    {
        int c = t >> 1, h = t & 1;      // col 0..127, half 0/1 (32 n each)
        float sx = 0.f;
        #pragma unroll
        for (int rr = 0; rr < 32; rr++) sx += bf2f(xt[h * 32 + rr][c]);
        sx += __shfl_xor(sx, 1);        // combine the two halves of col c
        if (h == 0) sxp[((size_t)(b * LNCH + ch)) * DD + c] = sx;
    }
}

// ------------------------------------------------------------------
__global__ __launch_bounds__(512) void k_sumx(const float* __restrict__ sxp,
                                              float* __restrict__ sumx) {
    int b = blockIdx.x, t = threadIdx.x;
    int c = t & 127, g = t >> 7;        // 4 groups of 64 chunks
    __shared__ float part[4][DD];
    float s = 0.f;
    for (int cb = g * 64; cb < (g + 1) * 64; cb++)
        s += sxp[((size_t)(b * LNCH + cb)) * DD + c];
    part[g][c] = s;
    __syncthreads();
    if (t < DD) sumx[b * DD + t] = part[0][t] + part[1][t] + part[2][t] + part[3][t];
}

// ------------------------------------------------------------------
__device__ inline void block_stats(float v, float& mean, float& rstd, float* red) {
    float s = v, sq = v * v;
    #pragma unroll
    for (int o = 32; o > 0; o >>= 1) {
        s  += __shfl_down(s, o, 64);
        sq += __shfl_down(sq, o, 64);
    }
    int lane = threadIdx.x & 63, w = threadIdx.x >> 6;
    if (lane == 0) { red[w * 2] = s; red[w * 2 + 1] = sq; }
    __syncthreads();
    float S = red[0] + red[2], SQ = red[1] + red[3];
    mean = S * (1.0f / DD);
    float var = SQ * (1.0f / DD) - mean * mean;
    rstd = rsqrtf(var + LN_EPS);
    __syncthreads();
}

// ------------------------------------------------------------------
// slots init; q = LN(slots)@Wq + bq; qp = SCALE*(q@WkT); qc0 = SCALE*(q.bk)
__global__ __launch_bounds__(128) void k_init(
        const float* __restrict__ noise, const float* __restrict__ mu,
        const float* __restrict__ logsigma,
        const float* __restrict__ Wq, const float* __restrict__ bq,
        const float* __restrict__ WkT, const float* __restrict__ bk,
        const float* __restrict__ g_sl, const float* __restrict__ b_sl,
        float* __restrict__ slots, float* __restrict__ qp,
        float* __restrict__ qc0) {
    int bk_ = blockIdx.x;
    int j = threadIdx.x;
    __shared__ float red[4];
    __shared__ float tmp[DD], q_l[DD];
    float s = mu[j] + __expf(logsigma[j]) * noise[bk_ * DD + j];
    slots[bk_ * DD + j] = s;
    float m, rs;
    block_stats(s, m, rs, red);
    tmp[j] = (s - m) * rs * g_sl[j] + b_sl[j];
    __syncthreads();
    float qv = bq[j];
    for (int d = 0; d < DD; d++) qv += tmp[d] * Wq[d * DD + j];
    q_l[j] = qv;
    __syncthreads();
    float qq = 0.f;
    for (int d = 0; d < DD; d++) qq += q_l[d] * WkT[d * DD + j];
    qp[bk_ * DD + j] = SCALE * qq;
    float cp = q_l[j] * bk[j];
    #pragma unroll
    for (int o = 32; o > 0; o >>= 1) cp += __shfl_xor(cp, o);
    if ((j & 63) == 0) red[j >> 6] = cp;
    __syncthreads();
    if (j == 0) qc0[bk_] = SCALE * (red[0] + red[1]);
}

// ------------------------------------------------------------------
// MFMA attention iteration. xn is the only N-sized input.
// dots^T:  C[n][slot] = xn[n][:] . qp[slot][:] + c0[slot]
// PV:      C'[slot][d] = sum_n P^T[slot][n] . xn[n][d]
//   A = P^T from plds (strided u16), B = xn column-slice (u16 gather,
//   tile is L1/L2-hot from the QK^T pass). No xnT anywhere.
__global__ __launch_bounds__(256) void k_attn(
        const ushort* __restrict__ xn,
        const float* __restrict__ qp, const float* __restrict__ qc0,
        float* __restrict__ upart, float* __restrict__ dpart,
        float* __restrict__ out_s, int last) {
    __shared__ ushort qlds[16][136];   // qp bf16, rows 10-15 zero
    __shared__ ushort plds[NB][18];    // P bf16 [n][slot], pad 18
    __shared__ float red2[4][16];
    __shared__ float c0s[16];

    int t = threadIdx.x;
    int blk = blockIdx.x;
    int b  = blk >> 7;
    int ch = blk & (NCH - 1);
    int n0 = ch * NB;
    int w = t >> 6, l = t & 63;
    int lc = l & 15, lg = l >> 4;

    for (int j = t; j < 16 * DD; j += 256) {
        int row = j >> 7, col = j & 127;
        float v = (row < KK) ? qp[((size_t)b * KK + row) * DD + col] : 0.f;
        qlds[row][col] = f2bf(v);
    }
    if (t < 16) c0s[t] = (t < KK) ? qc0[b * KK + t] : 0.f;
    __syncthreads();

    // qp B-frags: B[k=d][col=slot] -> qlds[lc][ks*32+lg*8+j]
    bf16x8 qb[4];
    #pragma unroll
    for (int ks = 0; ks < 4; ks++)
        qb[ks] = *(const bf16x8*)&qlds[lc][ks * 32 + lg * 8];
    float c0v = c0s[lc];

    float dsum = 0.f;
    bool valid = lc < KK;
    #pragma unroll
    for (int tt = 0; tt < 2; tt++) {
        int nt = w * 2 + tt;    // n-tile 0..7
        const ushort* kb = xn + ((size_t)(b * NN + n0 + nt * 16 + lc)) * DD + lg * 8;
        f32x4 acc = (f32x4){0.f, 0.f, 0.f, 0.f};
        #pragma unroll
        for (int ks = 0; ks < 4; ks++) {
            bf16x8 a = *(const bf16x8*)(kb + ks * 32);   // 16B coalesced
            acc = __builtin_amdgcn_mfma_f32_16x16x32_bf16(a, qb[ks], acc, 0, 0, 0);
        }
        // softmax per row (n); C layout: row=(l>>4)*4+r, col=slot=lc
        #pragma unroll
        for (int r = 0; r < 4; r++) {
            float v = acc[r] + c0v;
            float m = valid ? v : -3.0e38f;
            m = fmaxf(m, __shfl_xor(m, 1));
            m = fmaxf(m, __shfl_xor(m, 2));
            m = fmaxf(m, __shfl_xor(m, 4));
            m = fmaxf(m, __shfl_xor(m, 8));
            float e = valid ? __expf(v - m) : 0.f;
            float s = e;
            s += __shfl_xor(s, 1);
            s += __shfl_xor(s, 2);
            s += __shfl_xor(s, 4);
            s += __shfl_xor(s, 8);
            float p = e / s;
            dsum += p;
            plds[nt * 16 + lg * 4 + r][lc] = f2bf(p);
        }
    }
    // denom partial: sum over this wave's 32 n, per slot
    dsum += __shfl_xor(dsum, 16);
    dsum += __shfl_xor(dsum, 32);
    if (l < 16) red2[w][l] = dsum;
    __syncthreads();

    if (t < KK)
        dpart[((size_t)b * NCH + ch) * KK + t] =
            red2[0][t] + red2[1][t] + red2[2][t] + red2[3][t];

    // PV A-frags: A[m=slot][k=n] -> plds[ks*32+lg*8+j][lc]
    bf16x8 pa[4];
    #pragma unroll
    for (int ks = 0; ks < 4; ks++) {
        #pragma unroll
        for (int j = 0; j < 8; j++)
            pa[ks][j] = (short)plds[ks * 32 + lg * 8 + j][lc];
    }

    float* ud = upart + ((size_t)b * NCH + ch) * KK * DD;
    #pragma unroll
    for (int tt = 0; tt < 2; tt++) {
        int dt = w * 2 + tt;    // d-tile 0..7
        // B = xn[n][dt*16+lc]: per-lane u16 gather down the column slice
        const ushort* vb = xn + ((size_t)(b * NN + n0)) * DD + dt * 16 + lc;
        f32x4 uacc = (f32x4){0.f, 0.f, 0.f, 0.f};
        #pragma unroll
        for (int ks = 0; ks < 4; ks++) {
            bf16x8 bf;
            #pragma unroll
            for (int j = 0; j < 8; j++)
                bf[j] = (short)vb[(size_t)(ks * 32 + lg * 8 + j) * DD];
            uacc = __builtin_amdgcn_mfma_f32_16x16x32_bf16(pa[ks], bf, uacc, 0, 0, 0);
        }
        // C layout: row = slot = lg*4+r, col = d-within-tile = lc
        #pragma unroll
        for (int r = 0; r < 4; r++) {
            int slot = lg * 4 + r;
            if (slot < KK)
                ud[slot * DD + dt * 16 + lc] = uacc[r];
        }
    }

    if (last) {
        for (int i = t; i < NB * KK; i += 256) {
            int n = i / KK, s2 = i - n * KK;
            out_s[((size_t)b * NN + n0 + n) * KK + s2] = bf2f(plds[n][s2]);
        }
    }
}

// ------------------------------------------------------------------
// Reduce partials -> Yw; updates = Yw@Wv + bv; GRU; LN+MLP; next qp/qc0.
__global__ __launch_bounds__(384) void k_slot(
        const float* __restrict__ upart, const float* __restrict__ dpart,
        const float* __restrict__ sumx,
        const float* __restrict__ Wv, const float* __restrict__ bv,
        const float* __restrict__ WihT, const float* __restrict__ WhhT,
        const float* __restrict__ bih, const float* __restrict__ bhh,
        const float* __restrict__ W1, const float* __restrict__ b1,
        const float* __restrict__ W2, const float* __restrict__ b2,
        const float* __restrict__ Wq, const float* __restrict__ bq,
        const float* __restrict__ WkT, const float* __restrict__ bk,
        const float* __restrict__ g_ff, const float* __restrict__ b_ff,
        const float* __restrict__ g_sl, const float* __restrict__ b_sl,
        float* __restrict__ slots, float* __restrict__ qp,
        float* __restrict__ qc0,
        float* __restrict__ out_nf, float* __restrict__ out_adj, int last) {
    int blk = blockIdx.x;
    int b = blk / KK, kslot = blk % KK;
    int t = threadIdx.x;
    __shared__ float u_lds[DD], p_lds[DD], tmp[DD], y_lds[DD], q_l[DD];
    __shared__ float gi_lds[3 * DD], gh_lds[3 * DD];
    __shared__ float upr[3][DD];
    __shared__ float red[8];

    // --- u partial reduce (strided over 128 chunks) ---
    {
        int j = t & 127, g = t >> 7;
        int c0 = g * 43, c1 = (g == 2) ? NCH : c0 + 43;
        float u = 0.f;
        const float* up = upart + (size_t)b * NCH * KK * DD + kslot * DD + j;
        for (int c = c0; c < c1; c++) u += up[(size_t)c * KK * DD];
        upr[g][j] = u;
    }
    // --- denom: 64 threads, 2 chunks each, shfl reduce ---
    {
        float dsv = 0.f;
        if (t < 64) {
            const float* dp = dpart + (size_t)b * NCH * KK + kslot;
            dsv = dp[(size_t)(2 * t) * KK] + dp[(size_t)(2 * t + 1) * KK];
        }
        #pragma unroll
        for (int o = 32; o > 0; o >>= 1) dsv += __shfl_xor(dsv, o);
        if (t == 0) red[6] = dsv + (float)NN * ATT_EPS;
    }
    __syncthreads();

    float prev = 0.f;
    if (t < DD) {
        float u = upr[0][t] + upr[1][t] + upr[2][t];
        y_lds[t] = (u + ATT_EPS * sumx[b * DD + t]) / red[6];   // Yw
        prev = slots[(b * KK + kslot) * DD + t];
        p_lds[t] = prev;
    }
    __syncthreads();

    // --- updates = Yw @ Wv + bv (folded V projection) ---
    if (t < DD) {
        float upd = bv[t];
        for (int d4 = 0; d4 < DD / 4; d4++) {
            float4 yv = *(const float4*)&y_lds[d4 * 4];
            const float* wp = Wv + (size_t)(d4 * 4) * DD + t;
            upd += yv.x * wp[0] + yv.y * wp[DD] + yv.z * wp[2 * DD] + yv.w * wp[3 * DD];
        }
        u_lds[t] = upd;
    }
    __syncthreads();

    // --- gi/gh: one column per thread (384 columns) ---
    {
        float gi = bih[t], gh = bhh[t];
        for (int d4 = 0; d4 < DD / 4; d4++) {
            float4 uv = *(const float4*)&u_lds[d4 * 4];
            float4 pv = *(const float4*)&p_lds[d4 * 4];
            const float* wi = WihT + (size_t)(d4 * 4) * 3 * DD + t;
            const float* wh = WhhT + (size_t)(d4 * 4) * 3 * DD + t;
            gi += uv.x * wi[0] + uv.y * wi[3 * DD] + uv.z * wi[6 * DD] + uv.w * wi[9 * DD];
            gh += pv.x * wh[0] + pv.y * wh[3 * DD] + pv.z * wh[6 * DD] + pv.w * wh[9 * DD];
        }
        gi_lds[t] = gi;
        gh_lds[t] = gh;
    }
    __syncthreads();

    float snew = 0.f;
    if (t < DD) {
        float r = 1.f / (1.f + __expf(-(gi_lds[t] + gh_lds[t])));
        float z = 1.f / (1.f + __expf(-(gi_lds[DD + t] + gh_lds[DD + t])));
        float nn_ = tanhf(gi_lds[2 * DD + t] + r * gh_lds[2 * DD + t]);
        snew = (1.f - z) * nn_ + z * prev;
    }
    // --- LN(snew) ---
    {
        float s_ = (t < DD) ? snew : 0.f, sq_ = s_ * s_;
        #pragma unroll
        for (int o = 32; o > 0; o >>= 1) { s_ += __shfl_xor(s_, o); sq_ += __shfl_xor(sq_, o); }
        if (t < DD && (t & 63) == 0) { red[(t >> 6) * 2] = s_; red[(t >> 6) * 2 + 1] = sq_; }
    }
    __syncthreads();
    if (t < DD) {
        float mean = (red[0] + red[2]) * (1.0f / DD);
        float var  = (red[1] + red[3]) * (1.0f / DD) - mean * mean;
        float rstd = rsqrtf(var + LN_EPS);
        tmp[t] = (snew - mean) * rstd * g_ff[t] + b_ff[t];
    }
    __syncthreads();
    float h = 0.f;
    if (t < DD) {
        h = b1[t];
        for (int d4 = 0; d4 < DD / 4; d4++) {
            float4 tv = *(const float4*)&tmp[d4 * 4];
            const float* wp = W1 + (size_t)(d4 * 4) * DD + t;
            h += tv.x * wp[0] + tv.y * wp[DD] + tv.z * wp[2 * DD] + tv.w * wp[3 * DD];
        }
        h = fmaxf(h, 0.f);
    }
    __syncthreads();
    if (t < DD) tmp[t] = h;
    __syncthreads();
    float o = 0.f;
    if (t < DD) {
        o = snew + b2[t];
        for (int d4 = 0; d4 < DD / 4; d4++) {
            float4 tv = *(const float4*)&tmp[d4 * 4];
            const float* wp = W2 + (size_t)(d4 * 4) * DD + t;
            o += tv.x * wp[0] + tv.y * wp[DD] + tv.z * wp[2 * DD] + tv.w * wp[3 * DD];
        }
        slots[(b * KK + kslot) * DD + t] = o;
    }
    // --- LN(o) -> q -> qp/qc0 for next iteration ---
    {
        float s_ = (t < DD) ? o : 0.f, sq_ = s_ * s_;
        #pragma unroll
        for (int o2 = 32; o2 > 0; o2 >>= 1) { s_ += __shfl_xor(s_, o2); sq_ += __shfl_xor(sq_, o2); }
        if (t < DD && (t & 63) == 0) { red[(t >> 6) * 2] = s_; red[(t >> 6) * 2 + 1] = sq_; }
    }
    __syncthreads();
    if (t < DD) {
        float mean = (red[0] + red[2]) * (1.0f / DD);
        float var  = (red[1] + red[3]) * (1.0f / DD) - mean * mean;
        float rstd = rsqrtf(var + LN_EPS);
        tmp[t] = (o - mean) * rstd * g_sl[t] + b_sl[t];
    }
    __syncthreads();
    if (t < DD) {
        float qv = bq[t];
        for (int d4 = 0; d4 < DD / 4; d4++) {
            float4 tv = *(const float4*)&tmp[d4 * 4];
            const float* wp = Wq + (size_t)(d4 * 4) * DD + t;
            qv += tv.x * wp[0] + tv.y * wp[DD] + tv.z * wp[2 * DD] + tv.w * wp[3 * DD];
        }
        q_l[t] = qv;
    }
    __syncthreads();
    if (t < DD) {
        float qq = 0.f;
        for (int d4 = 0; d4 < DD / 4; d4++) {
            float4 tv = *(const float4*)&q_l[d4 * 4];
            const float* wp = WkT + (size_t)(d4 * 4) * DD + t;
            qq += tv.x * wp[0] + tv.y * wp[DD] + tv.z * wp[2 * DD] + tv.w * wp[3 * DD];
        }
        qp[(b * KK + kslot) * DD + t] = SCALE * qq;
        if (last) {
            out_nf[(b * KK + kslot) * DD + t] = o;
            if (t < KK) out_adj[(b * KK + kslot) * KK + t] = 1.0f;
        }
    }
    {
        float cp = (t < DD) ? q_l[t] * bk[t] : 0.f;
        #pragma unroll
        for (int o2 = 32; o2 > 0; o2 >>= 1) cp += __shfl_xor(cp, o2);
        if (t < 128 && (t & 63) == 0) red[4 + (t >> 6)] = cp;
    }
    __syncthreads();
    if (t == 0) qc0[b * KK + kslot] = SCALE * (red[4] + red[5]);
}

// ------------------------------------------------------------------
extern "C" void kernel_launch(void* const* d_in, const int* in_sizes, int n_in,
                              void* d_out, int out_size, void* d_ws, size_t ws_size,
                              hipStream_t stream) {
    (void)in_sizes; (void)n_in; (void)out_size; (void)ws_size;
    const float* x        = (const float*)d_in[0];
    const float* noise    = (const float*)d_in[1];
    const float* mu       = (const float*)d_in[2];
    const float* logsigma = (const float*)d_in[3];
    const float* Wq  = (const float*)d_in[4];
    const float* bq  = (const float*)d_in[5];
    const float* Wk  = (const float*)d_in[6];
    const float* bk  = (const float*)d_in[7];
    const float* Wv  = (const float*)d_in[8];
    const float* bv  = (const float*)d_in[9];
    const float* Wih = (const float*)d_in[10];
    const float* Whh = (const float*)d_in[11];
    const float* bih = (const float*)d_in[12];
    const float* bhh = (const float*)d_in[13];
    const float* W1  = (const float*)d_in[14];
    const float* b1  = (const float*)d_in[15];
    const float* W2  = (const float*)d_in[16];
    const float* b2  = (const float*)d_in[17];
    const float* g_in = (const float*)d_in[18];
    const float* b_in = (const float*)d_in[19];
    const float* g_sl = (const float*)d_in[20];
    const float* b_sl = (const float*)d_in[21];
    const float* g_ff = (const float*)d_in[22];
    const float* b_ff = (const float*)d_in[23];

    float* w = (float*)d_ws;
    ushort* xn   = (ushort*)(w + OFF_XN);
    float* WkT   = w + OFF_WKT;
    float* qp    = w + OFF_Q;
    float* qc0   = w + OFF_QC0;
    float* slots = w + OFF_SLOTS;
    float* upart = w + OFF_UPART;
    float* dpart = w + OFF_DPART;
    float* sxp   = w + OFF_SXP;
    float* sumx  = w + OFF_SUMX;
    float* WihT  = w + OFF_WIHT;
    float* WhhT  = w + OFF_WHHT;

    float* out_nf  = (float*)d_out;                       // [B,K,D]
    float* out_adj = out_nf + BB * KK * DD;               // [B,K,K]
    float* out_s   = out_adj + BB * KK * KK;              // [B,N,K]

    k_prep<<<256, 256, 0, stream>>>(Wih, Whh, Wk, WihT, WhhT, WkT);
    k_ln<<<BB * LNCH, 256, 0, stream>>>(x, g_in, b_in, xn, sxp);
    k_sumx<<<BB, 512, 0, stream>>>(sxp, sumx);
    k_init<<<BB * KK, 128, 0, stream>>>(noise, mu, logsigma, Wq, bq, WkT, bk,
                                        g_sl, b_sl, slots, qp, qc0);

    for (int it = 0; it < N_ITERS; it++) {
        int last = (it == N_ITERS - 1) ? 1 : 0;
        k_attn<<<BB * NCH, 256, 0, stream>>>(xn, qp, qc0, upart, dpart,
                                             out_s, last);
        k_slot<<<BB * KK, 384, 0, stream>>>(upart, dpart, sumx, Wv, bv,
                                            WihT, WhhT, bih, bhh, W1, b1, W2, b2,
                                            Wq, bq, WkT, bk, g_ff, b_ff, g_sl, b_sl,
                                            slots, qp, qc0, out_nf, out_adj, last);
    }
}

// Round 10
// 310.395 us; speedup vs baseline: 1.1607x; 1.0365x over previous
//
#include <hip/hip_runtime.h>
#include <cstdint>

#define BB 8
#define NN 16384
#define DD 128
#define KK 10
#define N_ITERS 7
#define LN_EPS 1e-5f
#define ATT_EPS 1e-8f
#define SCALE 0.08838834764831845f   // D^-0.5

#define LNR 64                 // rows per ln block
#define LNCH (NN / LNR)        // 256 chunks per batch
#define NB 128                 // n per attn block
#define NCH (NN / NB)          // 128 chunks per batch

typedef __attribute__((ext_vector_type(8))) short bf16x8;
typedef __attribute__((ext_vector_type(4))) float f32x4;

__device__ inline ushort f2bf(float f) {
    uint u = __builtin_bit_cast(uint, f);
    u += 0x7FFFu + ((u >> 16) & 1u);
    return (ushort)(u >> 16);
}
__device__ inline float bf2f(ushort u) {
    return __builtin_bit_cast(float, ((uint)u) << 16);
}

// ---- workspace layout (float units) ----
#define OFF_XN    ((size_t)0)
#define OFF_Q     (OFF_XN + (size_t)BB * NN * DD / 2)
#define OFF_QC0   (OFF_Q + (size_t)BB * KK * DD)
#define OFF_SLOTS (OFF_QC0 + 128)
#define OFF_UPART (OFF_SLOTS + (size_t)BB * KK * DD)
#define OFF_DPART (OFF_UPART + (size_t)BB * NCH * KK * DD)
#define OFF_SXP   (OFF_DPART + (size_t)BB * NCH * KK)
#define OFF_SUMX  (OFF_SXP + (size_t)BB * LNCH * DD)
#define OFF_WIHT  (OFF_SUMX + (size_t)BB * DD)
#define OFF_WHHT  (OFF_WIHT + (size_t)3 * DD * DD)
#define OFF_WVIH  (OFF_WHHT + (size_t)3 * DD * DD)
#define OFF_BVIH  (OFF_WVIH + (size_t)DD * 3 * DD)
#define OFF_M     (OFF_BVIH + (size_t)3 * DD)
#define OFF_V0    (OFF_M + (size_t)DD * DD)
#define OFF_WQBK  (OFF_V0 + (size_t)DD)
#define OFF_C1    (OFF_WQBK + (size_t)DD)

// ------------------------------------------------------------------
// Prep: transposes + folded weight products (all one-time, fp32 exact).
//  WihT/WhhT: [D][3D] transposes
//  Wvih[d][t] = sum_e Wv[d][e]*Wih[t][e]      (updates->gi fold)
//  bvih[t]    = sum_e bv[e]*Wih[t][e] + bih[t]
//  M[d][e]    = sum_j Wq[d][j]*Wk[e][j]       (q->qp fold)
//  v0[e]      = sum_j bq[j]*Wk[e][j]
//  wqbk[d]    = sum_j Wq[d][j]*bk[j],  c1 = bq.bk
__global__ void k_prep(const float* __restrict__ Wih, const float* __restrict__ Whh,
                       const float* __restrict__ Wq, const float* __restrict__ Wk,
                       const float* __restrict__ Wv,
                       const float* __restrict__ bih, const float* __restrict__ bv,
                       const float* __restrict__ bq, const float* __restrict__ bk,
                       float* __restrict__ WihT, float* __restrict__ WhhT,
                       float* __restrict__ Wvih, float* __restrict__ bvih,
                       float* __restrict__ M, float* __restrict__ v0,
                       float* __restrict__ wqbk, float* __restrict__ c1) {
    int idx = blockIdx.x * 256 + threadIdx.x;
    if (idx < 3 * DD * DD) {
        int d = idx / (3 * DD);
        int j = idx % (3 * DD);
        WihT[idx] = Wih[j * DD + d];
        WhhT[idx] = Whh[j * DD + d];
    } else if (idx < 2 * 3 * DD * DD) {
        int i = idx - 3 * DD * DD;
        int d = i / (3 * DD), t = i % (3 * DD);
        float s = 0.f;
        for (int e = 0; e < DD; e++) s += Wv[d * DD + e] * Wih[t * DD + e];
        Wvih[i] = s;
    } else if (idx < 2 * 3 * DD * DD + 3 * DD) {
        int t = idx - 2 * 3 * DD * DD;
        float s = bih[t];
        for (int e = 0; e < DD; e++) s += bv[e] * Wih[t * DD + e];
        bvih[t] = s;
    } else if (idx < 2 * 3 * DD * DD + 3 * DD + DD * DD) {
        int i = idx - (2 * 3 * DD * DD + 3 * DD);
        int d = i / DD, e = i % DD;
        float s = 0.f;
        for (int j = 0; j < DD; j++) s += Wq[d * DD + j] * Wk[e * DD + j];
        M[i] = s;
    } else if (idx < 2 * 3 * DD * DD + 3 * DD + DD * DD + DD) {
        int e = idx - (2 * 3 * DD * DD + 3 * DD + DD * DD);
        float s = 0.f;
        for (int j = 0; j < DD; j++) s += bq[j] * Wk[e * DD + j];
        v0[e] = s;
    } else if (idx < 2 * 3 * DD * DD + 3 * DD + DD * DD + 2 * DD) {
        int d = idx - (2 * 3 * DD * DD + 3 * DD + DD * DD + DD);
        float s = 0.f;
        for (int j = 0; j < DD; j++) s += Wq[d * DD + j] * bk[j];
        wqbk[d] = s;
    } else if (idx == 2 * 3 * DD * DD + 3 * DD + DD * DD + 2 * DD) {
        float s = 0.f;
        for (int j = 0; j < DD; j++) s += bq[j] * bk[j];
        c1[0] = s;
    }
}
#define PREP_TOTAL (2 * 3 * DD * DD + 3 * DD + DD * DD + 2 * DD + 1)

// ------------------------------------------------------------------
// Pure LayerNorm: x -> xn (row-major bf16) + sxp (partial column sums).
__global__ __launch_bounds__(256) void k_ln(
        const float* __restrict__ x,
        const float* __restrict__ g_in, const float* __restrict__ b_in,
        ushort* __restrict__ xn, float* __restrict__ sxp) {
    __shared__ ushort xt[LNR][136];

    int t = threadIdx.x, blk = blockIdx.x;
    int b = blk >> 8, ch = blk & (LNCH - 1);
    int n0 = ch * LNR;

    {
        int r = t >> 2, p = t & 3;
        const float4* xr = (const float4*)(x + ((size_t)(b * NN + n0 + r)) * DD + p * 32);
        float4 xv[8];
        float s = 0.f, sq = 0.f;
        #pragma unroll
        for (int i = 0; i < 8; i++) {
            xv[i] = xr[i];
            s  += xv[i].x + xv[i].y + xv[i].z + xv[i].w;
            sq += xv[i].x * xv[i].x + xv[i].y * xv[i].y +
                  xv[i].z * xv[i].z + xv[i].w * xv[i].w;
        }
        s += __shfl_xor(s, 1);  sq += __shfl_xor(sq, 1);
        s += __shfl_xor(s, 2);  sq += __shfl_xor(sq, 2);
        float mean = s * (1.0f / DD);
        float var  = sq * (1.0f / DD) - mean * mean;
        float rstd = rsqrtf(var + LN_EPS);
        ushort* xno = xn + ((size_t)(b * NN + n0 + r)) * DD + p * 32;
        #pragma unroll
        for (int i = 0; i < 8; i++) {
            int c0 = p * 32 + i * 4;
            ushort4 uv;
            uv.x = f2bf((xv[i].x - mean) * rstd * g_in[c0 + 0] + b_in[c0 + 0]);
            uv.y = f2bf((xv[i].y - mean) * rstd * g_in[c0 + 1] + b_in[c0 + 1]);
            uv.z = f2bf((xv[i].z - mean) * rstd * g_in[c0 + 2] + b_in[c0 + 2]);
            uv.w = f2bf((xv[i].w - mean) * rstd * g_in[c0 + 3] + b_in[c0 + 3]);
            *(ushort4*)&xt[r][c0] = uv;
            *(ushort4*)(xno + i * 4) = uv;
        }
    }
    __syncthreads();

    {
        int c = t >> 1, h = t & 1;
        float sx = 0.f;
        #pragma unroll
        for (int rr = 0; rr < 32; rr++) sx += bf2f(xt[h * 32 + rr][c]);
        sx += __shfl_xor(sx, 1);
        if (h == 0) sxp[((size_t)(b * LNCH + ch)) * DD + c] = sx;
    }
}

// ------------------------------------------------------------------
__global__ __launch_bounds__(512) void k_sumx(const float* __restrict__ sxp,
                                              float* __restrict__ sumx) {
    int b = blockIdx.x, t = threadIdx.x;
    int c = t & 127, g = t >> 7;
    __shared__ float part[4][DD];
    float s = 0.f;
    for (int cb = g * 64; cb < (g + 1) * 64; cb++)
        s += sxp[((size_t)(b * LNCH + cb)) * DD + c];
    part[g][c] = s;
    __syncthreads();
    if (t < DD) sumx[b * DD + t] = part[0][t] + part[1][t] + part[2][t] + part[3][t];
}

// ------------------------------------------------------------------
__device__ inline void block_stats(float v, float& mean, float& rstd, float* red) {
    float s = v, sq = v * v;
    #pragma unroll
    for (int o = 32; o > 0; o >>= 1) {
        s  += __shfl_down(s, o, 64);
        sq += __shfl_down(sq, o, 64);
    }
    int lane = threadIdx.x & 63, w = threadIdx.x >> 6;
    if (lane == 0) { red[w * 2] = s; red[w * 2 + 1] = sq; }
    __syncthreads();
    float S = red[0] + red[2], SQ = red[1] + red[3];
    mean = S * (1.0f / DD);
    float var = SQ * (1.0f / DD) - mean * mean;
    rstd = rsqrtf(var + LN_EPS);
    __syncthreads();
}

// ------------------------------------------------------------------
// slots init; tmp = LN(slots); qp = SCALE*(tmp@M + v0); qc0 via wqbk/c1.
__global__ __launch_bounds__(128) void k_init(
        const float* __restrict__ noise, const float* __restrict__ mu,
        const float* __restrict__ logsigma,
        const float* __restrict__ M, const float* __restrict__ v0,
        const float* __restrict__ wqbk, const float* __restrict__ c1,
        const float* __restrict__ g_sl, const float* __restrict__ b_sl,
        float* __restrict__ slots, float* __restrict__ qp,
        float* __restrict__ qc0) {
    int bk_ = blockIdx.x;
    int j = threadIdx.x;
    __shared__ float red[4];
    __shared__ float tmp[DD];
    float s = mu[j] + __expf(logsigma[j]) * noise[bk_ * DD + j];
    slots[bk_ * DD + j] = s;
    float m, rs;
    block_stats(s, m, rs, red);
    tmp[j] = (s - m) * rs * g_sl[j] + b_sl[j];
    __syncthreads();
    float qq = v0[j];
    for (int d = 0; d < DD; d++) qq += tmp[d] * M[d * DD + j];
    qp[bk_ * DD + j] = SCALE * qq;
    float cp = tmp[j] * wqbk[j];
    #pragma unroll
    for (int o = 32; o > 0; o >>= 1) cp += __shfl_xor(cp, o);
    if ((j & 63) == 0) red[j >> 6] = cp;
    __syncthreads();
    if (j == 0) qc0[bk_] = SCALE * (red[0] + red[1] + c1[0]);
}

// ------------------------------------------------------------------
// MFMA attention iteration. xn is the only N-sized input; it is read
// ONCE from global per block (QK^T pass) and scattered into a swizzled
// [d][n] LDS tile, from which PV B-frags are vector ds_read_b128.
// plds aliases qlds (both 2176 u16) to keep LDS at 4 blocks/CU.
__global__ __launch_bounds__(256) void k_attn(
        const ushort* __restrict__ xn,
        const float* __restrict__ qp, const float* __restrict__ qc0,
        float* __restrict__ upart, float* __restrict__ dpart,
        float* __restrict__ out_s, int last) {
    __shared__ ushort qpbuf[2176];      // qlds [16][136] then plds [128][17]
    __shared__ ushort xlds[DD * 136];   // [d][n] pad 136, XOR-swizzled 16B slots
    __shared__ float red2[4][16];
    __shared__ float c0s[16];
#define QLDS(r, c) qpbuf[(r) * 136 + (c)]
#define PLDS(n, k) qpbuf[(n) * 17 + (k)]

    int t = threadIdx.x;
    int blk = blockIdx.x;
    int b  = blk >> 7;
    int ch = blk & (NCH - 1);
    int n0 = ch * NB;
    int w = t >> 6, l = t & 63;
    int lc = l & 15, lg = l >> 4;

    for (int j = t; j < 16 * DD; j += 256) {
        int row = j >> 7, col = j & 127;
        float v = (row < KK) ? qp[((size_t)b * KK + row) * DD + col] : 0.f;
        QLDS(row, col) = f2bf(v);
    }
    if (t < 16) c0s[t] = (t < KK) ? qc0[b * KK + t] : 0.f;
    __syncthreads();

    // qp B-frags: B[k=d][col=slot]
    bf16x8 qb[4];
    #pragma unroll
    for (int ks = 0; ks < 4; ks++)
        qb[ks] = *(const bf16x8*)&QLDS(lc, ks * 32 + lg * 8);
    float c0v = c0s[lc];
    __syncthreads();   // qpbuf now reusable as plds

    float dsum = 0.f;
    bool valid = lc < KK;
    #pragma unroll
    for (int tt = 0; tt < 2; tt++) {
        int nt = w * 2 + tt;    // n-tile 0..7
        int nrow = nt * 16 + lc;
        const ushort* kb = xn + ((size_t)(b * NN + n0 + nrow)) * DD + lg * 8;
        f32x4 acc = (f32x4){0.f, 0.f, 0.f, 0.f};
        #pragma unroll
        for (int ks = 0; ks < 4; ks++) {
            bf16x8 a = *(const bf16x8*)(kb + ks * 32);   // 16B coalesced
            // scatter to swizzled xlds[d][n]: d = ks*32+lg*8+j, n = nrow
            int dbase = ks * 32 + lg * 8;
            uint swz = (uint)(lg << 4);
            #pragma unroll
            for (int j = 0; j < 8; j++) {
                uint byteoff = ((uint)(dbase + j) * 272 + (uint)nrow * 2) ^ swz;
                *(ushort*)((char*)xlds + byteoff) = (ushort)a[j];
            }
            acc = __builtin_amdgcn_mfma_f32_16x16x32_bf16(a, qb[ks], acc, 0, 0, 0);
        }
        // softmax per row (n); C layout: row=(l>>4)*4+r, col=slot=lc
        #pragma unroll
        for (int r = 0; r < 4; r++) {
            float v = acc[r] + c0v;
            float m = valid ? v : -3.0e38f;
            m = fmaxf(m, __shfl_xor(m, 1));
            m = fmaxf(m, __shfl_xor(m, 2));
            m = fmaxf(m, __shfl_xor(m, 4));
            m = fmaxf(m, __shfl_xor(m, 8));
            float e = valid ? __expf(v - m) : 0.f;
            float s = e;
            s += __shfl_xor(s, 1);
            s += __shfl_xor(s, 2);
            s += __shfl_xor(s, 4);
            s += __shfl_xor(s, 8);
            float p = e / s;
            dsum += p;
            PLDS(nt * 16 + lg * 4 + r, lc) = f2bf(p);
        }
    }
    dsum += __shfl_xor(dsum, 16);
    dsum += __shfl_xor(dsum, 32);
    if (l < 16) red2[w][l] = dsum;
    __syncthreads();

    if (t < KK)
        dpart[((size_t)b * NCH + ch) * KK + t] =
            red2[0][t] + red2[1][t] + red2[2][t] + red2[3][t];

    // PV A-frags: A[m=slot][k=n] from plds (strided u16)
    bf16x8 pa[4];
    #pragma unroll
    for (int ks = 0; ks < 4; ks++) {
        #pragma unroll
        for (int j = 0; j < 8; j++)
            pa[ks][j] = (short)PLDS(ks * 32 + lg * 8 + j, lc);
    }

    float* ud = upart + ((size_t)b * NCH + ch) * KK * DD;
    #pragma unroll
    for (int tt = 0; tt < 2; tt++) {
        int dt = w * 2 + tt;    // d-tile 0..7
        int drow = dt * 16 + lc;
        uint rswz = (uint)(((drow >> 3) & 3) << 4);
        f32x4 uacc = (f32x4){0.f, 0.f, 0.f, 0.f};
        #pragma unroll
        for (int ks = 0; ks < 4; ks++) {
            // B[k=n][col=d] = xlds[drow][ks*32+lg*8 ..+7] (swizzled vector read)
            uint byteoff = ((uint)drow * 272 + (uint)(ks * 32 + lg * 8) * 2) ^ rswz;
            bf16x8 bf = *(const bf16x8*)((const char*)xlds + byteoff);
            uacc = __builtin_amdgcn_mfma_f32_16x16x32_bf16(pa[ks], bf, uacc, 0, 0, 0);
        }
        // C: row = slot = lg*4+r, col = d-in-tile = lc
        #pragma unroll
        for (int r = 0; r < 4; r++) {
            int slot = lg * 4 + r;
            if (slot < KK)
                ud[slot * DD + dt * 16 + lc] = uacc[r];
        }
    }

    if (last) {
        for (int i = t; i < NB * KK; i += 256) {
            int n = i / KK, s2 = i - n * KK;
            out_s[((size_t)b * NN + n0 + n) * KK + s2] = bf2f(PLDS(n, s2));
        }
    }
#undef QLDS
#undef PLDS
}

// ------------------------------------------------------------------
// Reduce partials -> Yw; gi = Yw@Wvih + bvih (folded); GRU; LN+MLP;
// qp = SCALE*(LN(o)@M + v0); qc0 = SCALE*(LN(o).wqbk + c1).
__global__ __launch_bounds__(384) void k_slot(
        const float* __restrict__ upart, const float* __restrict__ dpart,
        const float* __restrict__ sumx,
        const float* __restrict__ Wvih, const float* __restrict__ bvih,
        const float* __restrict__ WhhT, const float* __restrict__ bhh,
        const float* __restrict__ W1, const float* __restrict__ b1,
        const float* __restrict__ W2, const float* __restrict__ b2,
        const float* __restrict__ M, const float* __restrict__ v0,
        const float* __restrict__ wqbk, const float* __restrict__ c1,
        const float* __restrict__ g_ff, const float* __restrict__ b_ff,
        const float* __restrict__ g_sl, const float* __restrict__ b_sl,
        float* __restrict__ slots, float* __restrict__ qp,
        float* __restrict__ qc0,
        float* __restrict__ out_nf, float* __restrict__ out_adj, int last) {
    int blk = blockIdx.x;
    int b = blk / KK, kslot = blk % KK;
    int t = threadIdx.x;
    __shared__ float p_lds[DD], tmp[DD], y_lds[DD];
    __shared__ float gi_lds[3 * DD], gh_lds[3 * DD];
    __shared__ float upr[3][DD];
    __shared__ float red[8];

    // --- u partial reduce (strided over 128 chunks) ---
    {
        int j = t & 127, g = t >> 7;
        int c0 = g * 43, c1_ = (g == 2) ? NCH : c0 + 43;
        float u = 0.f;
        const float* up = upart + (size_t)b * NCH * KK * DD + kslot * DD + j;
        for (int c = c0; c < c1_; c++) u += up[(size_t)c * KK * DD];
        upr[g][j] = u;
    }
    // --- denom ---
    {
        float dsv = 0.f;
        if (t < 64) {
            const float* dp = dpart + (size_t)b * NCH * KK + kslot;
            dsv = dp[(size_t)(2 * t) * KK] + dp[(size_t)(2 * t + 1) * KK];
        }
        #pragma unroll
        for (int o = 32; o > 0; o >>= 1) dsv += __shfl_xor(dsv, o);
        if (t == 0) red[6] = dsv + (float)NN * ATT_EPS;
    }
    __syncthreads();

    float prev = 0.f;
    if (t < DD) {
        float u = upr[0][t] + upr[1][t] + upr[2][t];
        y_lds[t] = (u + ATT_EPS * sumx[b * DD + t]) / red[6];   // Yw
        prev = slots[(b * KK + kslot) * DD + t];
        p_lds[t] = prev;
    }
    __syncthreads();

    // --- gi/gh: one gate-column per thread (384) ---
    {
        float gi = bvih[t], gh = bhh[t];
        for (int d4 = 0; d4 < DD / 4; d4++) {
            float4 yv = *(const float4*)&y_lds[d4 * 4];
            float4 pv = *(const float4*)&p_lds[d4 * 4];
            const float* wi = Wvih + (size_t)(d4 * 4) * 3 * DD + t;
            const float* wh = WhhT + (size_t)(d4 * 4) * 3 * DD + t;
            gi += yv.x * wi[0] + yv.y * wi[3 * DD] + yv.z * wi[6 * DD] + yv.w * wi[9 * DD];
            gh += pv.x * wh[0] + pv.y * wh[3 * DD] + pv.z * wh[6 * DD] + pv.w * wh[9 * DD];
        }
        gi_lds[t] = gi;
        gh_lds[t] = gh;
    }
    __syncthreads();

    float snew = 0.f;
    if (t < DD) {
        float r = 1.f / (1.f + __expf(-(gi_lds[t] + gh_lds[t])));
        float z = 1.f / (1.f + __expf(-(gi_lds[DD + t] + gh_lds[DD + t])));
        float nn_ = tanhf(gi_lds[2 * DD + t] + r * gh_lds[2 * DD + t]);
        snew = (1.f - z) * nn_ + z * prev;
    }
    // --- LN(snew) ---
    {
        float s_ = (t < DD) ? snew : 0.f, sq_ = s_ * s_;
        #pragma unroll
        for (int o = 32; o > 0; o >>= 1) { s_ += __shfl_xor(s_, o); sq_ += __shfl_xor(sq_, o); }
        if (t < DD && (t & 63) == 0) { red[(t >> 6) * 2] = s_; red[(t >> 6) * 2 + 1] = sq_; }
    }
    __syncthreads();
    if (t < DD) {
        float mean = (red[0] + red[2]) * (1.0f / DD);
        float var  = (red[1] + red[3]) * (1.0f / DD) - mean * mean;
        float rstd = rsqrtf(var + LN_EPS);
        tmp[t] = (snew - mean) * rstd * g_ff[t] + b_ff[t];
    }
    __syncthreads();
    float h = 0.f;
    if (t < DD) {
        h = b1[t];
        for (int d4 = 0; d4 < DD / 4; d4++) {
            float4 tv = *(const float4*)&tmp[d4 * 4];
            const float* wp = W1 + (size_t)(d4 * 4) * DD + t;
            h += tv.x * wp[0] + tv.y * wp[DD] + tv.z * wp[2 * DD] + tv.w * wp[3 * DD];
        }
        h = fmaxf(h, 0.f);
    }
    __syncthreads();
    if (t < DD) tmp[t] = h;
    __syncthreads();
    float o = 0.f;
    if (t < DD) {
        o = snew + b2[t];
        for (int d4 = 0; d4 < DD / 4; d4++) {
            float4 tv = *(const float4*)&tmp[d4 * 4];
            const float* wp = W2 + (size_t)(d4 * 4) * DD + t;
            o += tv.x * wp[0] + tv.y * wp[DD] + tv.z * wp[2 * DD] + tv.w * wp[3 * DD];
        }
        slots[(b * KK + kslot) * DD + t] = o;
    }
    // --- LN(o) -> qp/qc0 via folded M/v0/wqbk/c1 ---
    {
        float s_ = (t < DD) ? o : 0.f, sq_ = s_ * s_;
        #pragma unroll
        for (int o2 = 32; o2 > 0; o2 >>= 1) { s_ += __shfl_xor(s_, o2); sq_ += __shfl_xor(sq_, o2); }
        if (t < DD && (t & 63) == 0) { red[(t >> 6) * 2] = s_; red[(t >> 6) * 2 + 1] = sq_; }
    }
    __syncthreads();
    if (t < DD) {
        float mean = (red[0] + red[2]) * (1.0f / DD);
        float var  = (red[1] + red[3]) * (1.0f / DD) - mean * mean;
        float rstd = rsqrtf(var + LN_EPS);
        tmp[t] = (o - mean) * rstd * g_sl[t] + b_sl[t];
    }
    __syncthreads();
    if (t < DD) {
        float qq = v0[t];
        for (int d4 = 0; d4 < DD / 4; d4++) {
            float4 tv = *(const float4*)&tmp[d4 * 4];
            const float* wp = M + (size_t)(d4 * 4) * DD + t;
            qq += tv.x * wp[0] + tv.y * wp[DD] + tv.z * wp[2 * DD] + tv.w * wp[3 * DD];
        }
        qp[(b * KK + kslot) * DD + t] = SCALE * qq;
        if (last) {
            out_nf[(b * KK + kslot) * DD + t] = o;
            if (t < KK) out_adj[(b * KK + kslot) * KK + t] = 1.0f;
        }
    }
    {
        float cp = (t < DD) ? tmp[t] * wqbk[t] : 0.f;
        #pragma unroll
        for (int o2 = 32; o2 > 0; o2 >>= 1) cp += __shfl_xor(cp, o2);
        if (t < 128 && (t & 63) == 0) red[4 + (t >> 6)] = cp;
    }
    __syncthreads();
    if (t == 0) qc0[b * KK + kslot] = SCALE * (red[4] + red[5] + c1[0]);
}

// ------------------------------------------------------------------
extern "C" void kernel_launch(void* const* d_in, const int* in_sizes, int n_in,
                              void* d_out, int out_size, void* d_ws, size_t ws_size,
                              hipStream_t stream) {
    (void)in_sizes; (void)n_in; (void)out_size; (void)ws_size;
    const float* x        = (const float*)d_in[0];
    const float* noise    = (const float*)d_in[1];
    const float* mu       = (const float*)d_in[2];
    const float* logsigma = (const float*)d_in[3];
    const float* Wq  = (const float*)d_in[4];
    const float* bq  = (const float*)d_in[5];
    const float* Wk  = (const float*)d_in[6];
    const float* bk  = (const float*)d_in[7];
    const float* Wv  = (const float*)d_in[8];
    const float* bv  = (const float*)d_in[9];
    const float* Wih = (const float*)d_in[10];
    const float* Whh = (const float*)d_in[11];
    const float* bih = (const float*)d_in[12];
    const float* bhh = (const float*)d_in[13];
    const float* W1  = (const float*)d_in[14];
    const float* b1  = (const float*)d_in[15];
    const float* W2  = (const float*)d_in[16];
    const float* b2  = (const float*)d_in[17];
    const float* g_in = (const float*)d_in[18];
    const float* b_in = (const float*)d_in[19];
    const float* g_sl = (const float*)d_in[20];
    const float* b_sl = (const float*)d_in[21];
    const float* g_ff = (const float*)d_in[22];
    const float* b_ff = (const float*)d_in[23];

    float* w = (float*)d_ws;
    ushort* xn   = (ushort*)(w + OFF_XN);
    float* qp    = w + OFF_Q;
    float* qc0   = w + OFF_QC0;
    float* slots = w + OFF_SLOTS;
    float* upart = w + OFF_UPART;
    float* dpart = w + OFF_DPART;
    float* sxp   = w + OFF_SXP;
    float* sumx  = w + OFF_SUMX;
    float* WihT  = w + OFF_WIHT;
    float* WhhT  = w + OFF_WHHT;
    float* Wvih  = w + OFF_WVIH;
    float* bvih  = w + OFF_BVIH;
    float* Mw    = w + OFF_M;
    float* v0    = w + OFF_V0;
    float* wqbk  = w + OFF_WQBK;
    float* c1    = w + OFF_C1;

    float* out_nf  = (float*)d_out;                       // [B,K,D]
    float* out_adj = out_nf + BB * KK * DD;               // [B,K,K]
    float* out_s   = out_adj + BB * KK * KK;              // [B,N,K]

    k_prep<<<(PREP_TOTAL + 255) / 256, 256, 0, stream>>>(
        Wih, Whh, Wq, Wk, Wv, bih, bv, bq, bk,
        WihT, WhhT, Wvih, bvih, Mw, v0, wqbk, c1);
    k_ln<<<BB * LNCH, 256, 0, stream>>>(x, g_in, b_in, xn, sxp);
    k_sumx<<<BB, 512, 0, stream>>>(sxp, sumx);
    k_init<<<BB * KK, 128, 0, stream>>>(noise, mu, logsigma, Mw, v0, wqbk, c1,
                                        g_sl, b_sl, slots, qp, qc0);

    for (int it = 0; it < N_ITERS; it++) {
        int last = (it == N_ITERS - 1) ? 1 : 0;
        k_attn<<<BB * NCH, 256, 0, stream>>>(xn, qp, qc0, upart, dpart,
                                             out_s, last);
        k_slot<<<BB * KK, 384, 0, stream>>>(upart, dpart, sumx,
                                            Wvih, bvih, WhhT, bhh, W1, b1, W2, b2,
                                            Mw, v0, wqbk, c1, g_ff, b_ff, g_sl, b_sl,
                                            slots, qp, qc0, out_nf, out_adj, last);
    }
}

// Round 11
// 249.127 us; speedup vs baseline: 1.4461x; 1.2459x over previous
//
#include <hip/hip_runtime.h>
#include <cstdint>

#define BB 8
#define NN 16384
#define DD 128
#define KK 10
#define N_ITERS 7
#define LN_EPS 1e-5f
#define ATT_EPS 1e-8f
#define SCALE 0.08838834764831845f   // D^-0.5

#define LNR 64                 // rows per ln block
#define LNCH (NN / LNR)        // 256 chunks per batch
#define NB 256                 // n per attn block (2 sub-tiles of 128)
#define NCH (NN / NB)          // 64 chunks per batch

typedef __attribute__((ext_vector_type(8))) short bf16x8;
typedef __attribute__((ext_vector_type(4))) float f32x4;

__device__ inline ushort f2bf(float f) {
    uint u = __builtin_bit_cast(uint, f);
    u += 0x7FFFu + ((u >> 16) & 1u);
    return (ushort)(u >> 16);
}
__device__ inline float bf2f(ushort u) {
    return __builtin_bit_cast(float, ((uint)u) << 16);
}

// ---- workspace layout (float units) ----
#define OFF_XN    ((size_t)0)
#define OFF_Q     (OFF_XN + (size_t)BB * NN * DD / 2)
#define OFF_QC0   (OFF_Q + (size_t)BB * KK * DD)
#define OFF_SLOTS (OFF_QC0 + 128)
#define OFF_UPART (OFF_SLOTS + (size_t)BB * KK * DD)
#define OFF_DPART (OFF_UPART + (size_t)BB * NCH * KK * DD)
#define OFF_SXP   (OFF_DPART + (size_t)BB * NCH * KK)
#define OFF_SUMX  (OFF_SXP + (size_t)BB * LNCH * DD)
#define OFF_WIHT  (OFF_SUMX + (size_t)BB * DD)
#define OFF_WHHT  (OFF_WIHT + (size_t)3 * DD * DD)
#define OFF_WVIH  (OFF_WHHT + (size_t)3 * DD * DD)
#define OFF_BVIH  (OFF_WVIH + (size_t)DD * 3 * DD)
#define OFF_M     (OFF_BVIH + (size_t)3 * DD)
#define OFF_V0    (OFF_M + (size_t)DD * DD)
#define OFF_WQBK  (OFF_V0 + (size_t)DD)
#define OFF_C1    (OFF_WQBK + (size_t)DD)

// ------------------------------------------------------------------
// Prep: transposes + folded weight products (one-time, fp32 exact).
__global__ void k_prep(const float* __restrict__ Wih, const float* __restrict__ Whh,
                       const float* __restrict__ Wq, const float* __restrict__ Wk,
                       const float* __restrict__ Wv,
                       const float* __restrict__ bih, const float* __restrict__ bv,
                       const float* __restrict__ bq, const float* __restrict__ bk,
                       float* __restrict__ WihT, float* __restrict__ WhhT,
                       float* __restrict__ Wvih, float* __restrict__ bvih,
                       float* __restrict__ M, float* __restrict__ v0,
                       float* __restrict__ wqbk, float* __restrict__ c1) {
    int idx = blockIdx.x * 256 + threadIdx.x;
    if (idx < 3 * DD * DD) {
        int d = idx / (3 * DD);
        int j = idx % (3 * DD);
        WihT[idx] = Wih[j * DD + d];
        WhhT[idx] = Whh[j * DD + d];
    } else if (idx < 2 * 3 * DD * DD) {
        int i = idx - 3 * DD * DD;
        int d = i / (3 * DD), t = i % (3 * DD);
        float s = 0.f;
        for (int e = 0; e < DD; e++) s += Wv[d * DD + e] * Wih[t * DD + e];
        Wvih[i] = s;
    } else if (idx < 2 * 3 * DD * DD + 3 * DD) {
        int t = idx - 2 * 3 * DD * DD;
        float s = bih[t];
        for (int e = 0; e < DD; e++) s += bv[e] * Wih[t * DD + e];
        bvih[t] = s;
    } else if (idx < 2 * 3 * DD * DD + 3 * DD + DD * DD) {
        int i = idx - (2 * 3 * DD * DD + 3 * DD);
        int d = i / DD, e = i % DD;
        float s = 0.f;
        for (int j = 0; j < DD; j++) s += Wq[d * DD + j] * Wk[e * DD + j];
        M[i] = s;
    } else if (idx < 2 * 3 * DD * DD + 3 * DD + DD * DD + DD) {
        int e = idx - (2 * 3 * DD * DD + 3 * DD + DD * DD);
        float s = 0.f;
        for (int j = 0; j < DD; j++) s += bq[j] * Wk[e * DD + j];
        v0[e] = s;
    } else if (idx < 2 * 3 * DD * DD + 3 * DD + DD * DD + 2 * DD) {
        int d = idx - (2 * 3 * DD * DD + 3 * DD + DD * DD + DD);
        float s = 0.f;
        for (int j = 0; j < DD; j++) s += Wq[d * DD + j] * bk[j];
        wqbk[d] = s;
    } else if (idx == 2 * 3 * DD * DD + 3 * DD + DD * DD + 2 * DD) {
        float s = 0.f;
        for (int j = 0; j < DD; j++) s += bq[j] * bk[j];
        c1[0] = s;
    }
}
#define PREP_TOTAL (2 * 3 * DD * DD + 3 * DD + DD * DD + 2 * DD + 1)

// ------------------------------------------------------------------
// Pure LayerNorm: x -> xn (row-major bf16) + sxp (partial column sums).
__global__ __launch_bounds__(256) void k_ln(
        const float* __restrict__ x,
        const float* __restrict__ g_in, const float* __restrict__ b_in,
        ushort* __restrict__ xn, float* __restrict__ sxp) {
    __shared__ ushort xt[LNR][136];

    int t = threadIdx.x, blk = blockIdx.x;
    int b = blk >> 8, ch = blk & (LNCH - 1);
    int n0 = ch * LNR;

    {
        int r = t >> 2, p = t & 3;
        const float4* xr = (const float4*)(x + ((size_t)(b * NN + n0 + r)) * DD + p * 32);
        float4 xv[8];
        float s = 0.f, sq = 0.f;
        #pragma unroll
        for (int i = 0; i < 8; i++) {
            xv[i] = xr[i];
            s  += xv[i].x + xv[i].y + xv[i].z + xv[i].w;
            sq += xv[i].x * xv[i].x + xv[i].y * xv[i].y +
                  xv[i].z * xv[i].z + xv[i].w * xv[i].w;
        }
        s += __shfl_xor(s, 1);  sq += __shfl_xor(sq, 1);
        s += __shfl_xor(s, 2);  sq += __shfl_xor(sq, 2);
        float mean = s * (1.0f / DD);
        float var  = sq * (1.0f / DD) - mean * mean;
        float rstd = rsqrtf(var + LN_EPS);
        ushort* xno = xn + ((size_t)(b * NN + n0 + r)) * DD + p * 32;
        #pragma unroll
        for (int i = 0; i < 8; i++) {
            int c0 = p * 32 + i * 4;
            ushort4 uv;
            uv.x = f2bf((xv[i].x - mean) * rstd * g_in[c0 + 0] + b_in[c0 + 0]);
            uv.y = f2bf((xv[i].y - mean) * rstd * g_in[c0 + 1] + b_in[c0 + 1]);
            uv.z = f2bf((xv[i].z - mean) * rstd * g_in[c0 + 2] + b_in[c0 + 2]);
            uv.w = f2bf((xv[i].w - mean) * rstd * g_in[c0 + 3] + b_in[c0 + 3]);
            *(ushort4*)&xt[r][c0] = uv;
            *(ushort4*)(xno + i * 4) = uv;
        }
    }
    __syncthreads();

    {
        int c = t >> 1, h = t & 1;
        float sx = 0.f;
        #pragma unroll
        for (int rr = 0; rr < 32; rr++) sx += bf2f(xt[h * 32 + rr][c]);
        sx += __shfl_xor(sx, 1);
        if (h == 0) sxp[((size_t)(b * LNCH + ch)) * DD + c] = sx;
    }
}

// ------------------------------------------------------------------
__global__ __launch_bounds__(512) void k_sumx(const float* __restrict__ sxp,
                                              float* __restrict__ sumx) {
    int b = blockIdx.x, t = threadIdx.x;
    int c = t & 127, g = t >> 7;
    __shared__ float part[4][DD];
    float s = 0.f;
    for (int cb = g * 64; cb < (g + 1) * 64; cb++)
        s += sxp[((size_t)(b * LNCH + cb)) * DD + c];
    part[g][c] = s;
    __syncthreads();
    if (t < DD) sumx[b * DD + t] = part[0][t] + part[1][t] + part[2][t] + part[3][t];
}

// ------------------------------------------------------------------
__device__ inline void block_stats(float v, float& mean, float& rstd, float* red) {
    float s = v, sq = v * v;
    #pragma unroll
    for (int o = 32; o > 0; o >>= 1) {
        s  += __shfl_down(s, o, 64);
        sq += __shfl_down(sq, o, 64);
    }
    int lane = threadIdx.x & 63, w = threadIdx.x >> 6;
    if (lane == 0) { red[w * 2] = s; red[w * 2 + 1] = sq; }
    __syncthreads();
    float S = red[0] + red[2], SQ = red[1] + red[3];
    mean = S * (1.0f / DD);
    float var = SQ * (1.0f / DD) - mean * mean;
    rstd = rsqrtf(var + LN_EPS);
    __syncthreads();
}

// ------------------------------------------------------------------
__global__ __launch_bounds__(128) void k_init(
        const float* __restrict__ noise, const float* __restrict__ mu,
        const float* __restrict__ logsigma,
        const float* __restrict__ M, const float* __restrict__ v0,
        const float* __restrict__ wqbk, const float* __restrict__ c1,
        const float* __restrict__ g_sl, const float* __restrict__ b_sl,
        float* __restrict__ slots, float* __restrict__ qp,
        float* __restrict__ qc0) {
    int bk_ = blockIdx.x;
    int j = threadIdx.x;
    __shared__ float red[4];
    __shared__ float tmp[DD];
    float s = mu[j] + __expf(logsigma[j]) * noise[bk_ * DD + j];
    slots[bk_ * DD + j] = s;
    float m, rs;
    block_stats(s, m, rs, red);
    tmp[j] = (s - m) * rs * g_sl[j] + b_sl[j];
    __syncthreads();
    float qq = v0[j];
    for (int d = 0; d < DD; d++) qq += tmp[d] * M[d * DD + j];
    qp[bk_ * DD + j] = SCALE * qq;
    float cp = tmp[j] * wqbk[j];
    #pragma unroll
    for (int o = 32; o > 0; o >>= 1) cp += __shfl_xor(cp, o);
    if ((j & 63) == 0) red[j >> 6] = cp;
    __syncthreads();
    if (j == 0) qc0[bk_] = SCALE * (red[0] + red[1] + c1[0]);
}

// ------------------------------------------------------------------
// MFMA attention iteration, NB=256 per block in 2 sub-tiles of 128.
// PV accumulates across sub-tiles in registers; xlds/plds reused.
__global__ __launch_bounds__(256) void k_attn(
        const ushort* __restrict__ xn,
        const float* __restrict__ qp, const float* __restrict__ qc0,
        float* __restrict__ upart, float* __restrict__ dpart,
        float* __restrict__ out_s, int last) {
    __shared__ ushort qpbuf[2176];      // qlds [16][136] then plds [128][17]
    __shared__ ushort xlds[DD * 136];   // [d][n(128)] pad, XOR-swizzled 16B slots
    __shared__ float red2[4][16];
    __shared__ float c0s[16];
#define QLDS(r, c) qpbuf[(r) * 136 + (c)]
#define PLDS(n, k) qpbuf[(n) * 17 + (k)]

    int t = threadIdx.x;
    int blk = blockIdx.x;
    int b  = blk >> 6;
    int ch = blk & (NCH - 1);
    int n0 = ch * NB;
    int w = t >> 6, l = t & 63;
    int lc = l & 15, lg = l >> 4;

    for (int j = t; j < 16 * DD; j += 256) {
        int row = j >> 7, col = j & 127;
        float v = (row < KK) ? qp[((size_t)b * KK + row) * DD + col] : 0.f;
        QLDS(row, col) = f2bf(v);
    }
    if (t < 16) c0s[t] = (t < KK) ? qc0[b * KK + t] : 0.f;
    __syncthreads();

    bf16x8 qb[4];
    #pragma unroll
    for (int ks = 0; ks < 4; ks++)
        qb[ks] = *(const bf16x8*)&QLDS(lc, ks * 32 + lg * 8);
    float c0v = c0s[lc];
    __syncthreads();   // qpbuf now reusable as plds

    f32x4 uacc[2];
    uacc[0] = (f32x4){0.f, 0.f, 0.f, 0.f};
    uacc[1] = (f32x4){0.f, 0.f, 0.f, 0.f};
    float dsum = 0.f;
    bool valid = lc < KK;

    for (int sub = 0; sub < 2; sub++) {
        int nbase = n0 + sub * 128;
        #pragma unroll
        for (int tt = 0; tt < 2; tt++) {
            int nt = w * 2 + tt;    // n-tile 0..7 within sub
            int nrow = nt * 16 + lc;
            const ushort* kb = xn + ((size_t)(b * NN + nbase + nrow)) * DD + lg * 8;
            f32x4 acc = (f32x4){0.f, 0.f, 0.f, 0.f};
            #pragma unroll
            for (int ks = 0; ks < 4; ks++) {
                bf16x8 a = *(const bf16x8*)(kb + ks * 32);   // 16B coalesced
                int dbase = ks * 32 + lg * 8;
                uint swz = (uint)(lg << 4);
                #pragma unroll
                for (int j = 0; j < 8; j++) {
                    uint byteoff = ((uint)(dbase + j) * 272 + (uint)nrow * 2) ^ swz;
                    *(ushort*)((char*)xlds + byteoff) = (ushort)a[j];
                }
                acc = __builtin_amdgcn_mfma_f32_16x16x32_bf16(a, qb[ks], acc, 0, 0, 0);
            }
            #pragma unroll
            for (int r = 0; r < 4; r++) {
                float v = acc[r] + c0v;
                float m = valid ? v : -3.0e38f;
                m = fmaxf(m, __shfl_xor(m, 1));
                m = fmaxf(m, __shfl_xor(m, 2));
                m = fmaxf(m, __shfl_xor(m, 4));
                m = fmaxf(m, __shfl_xor(m, 8));
                float e = valid ? __expf(v - m) : 0.f;
                float s = e;
                s += __shfl_xor(s, 1);
                s += __shfl_xor(s, 2);
                s += __shfl_xor(s, 4);
                s += __shfl_xor(s, 8);
                float p = e / s;
                dsum += p;
                PLDS(nt * 16 + lg * 4 + r, lc) = f2bf(p);
            }
        }
        __syncthreads();    // plds + xlds ready

        bf16x8 pa[4];
        #pragma unroll
        for (int ks = 0; ks < 4; ks++) {
            #pragma unroll
            for (int j = 0; j < 8; j++)
                pa[ks][j] = (short)PLDS(ks * 32 + lg * 8 + j, lc);
        }
        #pragma unroll
        for (int tt = 0; tt < 2; tt++) {
            int dt = w * 2 + tt;
            int drow = dt * 16 + lc;
            uint rswz = (uint)(((drow >> 3) & 3) << 4);
            #pragma unroll
            for (int ks = 0; ks < 4; ks++) {
                uint byteoff = ((uint)drow * 272 + (uint)(ks * 32 + lg * 8) * 2) ^ rswz;
                bf16x8 bf = *(const bf16x8*)((const char*)xlds + byteoff);
                uacc[tt] = __builtin_amdgcn_mfma_f32_16x16x32_bf16(pa[ks], bf, uacc[tt], 0, 0, 0);
            }
        }
        if (last) {
            for (int i = t; i < 128 * KK; i += 256) {
                int n = i / KK, s2 = i - n * KK;
                out_s[((size_t)b * NN + nbase + n) * KK + s2] = bf2f(PLDS(n, s2));
            }
        }
        __syncthreads();    // before next sub overwrites plds/xlds
    }

    dsum += __shfl_xor(dsum, 16);
    dsum += __shfl_xor(dsum, 32);
    if (l < 16) red2[w][l] = dsum;
    __syncthreads();
    if (t < KK)
        dpart[((size_t)b * NCH + ch) * KK + t] =
            red2[0][t] + red2[1][t] + red2[2][t] + red2[3][t];

    float* ud = upart + ((size_t)b * NCH + ch) * KK * DD;
    #pragma unroll
    for (int tt = 0; tt < 2; tt++) {
        int dt = w * 2 + tt;
        #pragma unroll
        for (int r = 0; r < 4; r++) {
            int slot = lg * 4 + r;
            if (slot < KK)
                ud[slot * DD + dt * 16 + lc] = uacc[tt][r];
        }
    }
#undef QLDS
#undef PLDS
}

// ------------------------------------------------------------------
// 768 threads: split-parallel matvecs, short serial chains.
__global__ __launch_bounds__(768) void k_slot(
        const float* __restrict__ upart, const float* __restrict__ dpart,
        const float* __restrict__ sumx,
        const float* __restrict__ Wvih, const float* __restrict__ bvih,
        const float* __restrict__ WhhT, const float* __restrict__ bhh,
        const float* __restrict__ W1, const float* __restrict__ b1,
        const float* __restrict__ W2, const float* __restrict__ b2,
        const float* __restrict__ M, const float* __restrict__ v0,
        const float* __restrict__ wqbk, const float* __restrict__ c1,
        const float* __restrict__ g_ff, const float* __restrict__ b_ff,
        const float* __restrict__ g_sl, const float* __restrict__ b_sl,
        float* __restrict__ slots, float* __restrict__ qp,
        float* __restrict__ qc0,
        float* __restrict__ out_nf, float* __restrict__ out_adj, int last) {
    int blk = blockIdx.x;
    int b = blk / KK, kslot = blk % KK;
    int t = threadIdx.x;
    __shared__ float p_lds[DD], tmp[DD], y_lds[DD];
    __shared__ float gi_lds[3 * DD], gh_lds[3 * DD];
    __shared__ float upr[6][DD];
    __shared__ float pp[4][DD];
    __shared__ float red[8];

    // --- u partial reduce over NCH=64 chunks, 6 groups ---
    {
        int j = t & 127, g = t >> 7;          // g = 0..5
        int c0 = (g * NCH) / 6, cend = ((g + 1) * NCH) / 6;
        const float* up = upart + (size_t)b * NCH * KK * DD + kslot * DD + j;
        float u = 0.f;
        for (int c = c0; c < cend; c++) u += up[(size_t)c * KK * DD];
        upr[g][j] = u;
    }
    // --- denom: 64 chunks, one per thread, shfl reduce ---
    {
        float dsv = 0.f;
        if (t < 64) dsv = dpart[((size_t)b * NCH + t) * KK + kslot];
        #pragma unroll
        for (int o = 32; o > 0; o >>= 1) dsv += __shfl_xor(dsv, o);
        if (t == 0) red[6] = dsv + (float)NN * ATT_EPS;
    }
    __syncthreads();

    float prev = 0.f;
    if (t < DD) {
        float u = upr[0][t] + upr[1][t] + upr[2][t] +
                  upr[3][t] + upr[4][t] + upr[5][t];
        y_lds[t] = (u + ATT_EPS * sumx[b * DD + t]) / red[6];   // Yw
        prev = slots[(b * KK + kslot) * DD + t];
        p_lds[t] = prev;
    }
    __syncthreads();

    // --- gi/gh: 768 threads, one gate-column each ---
    {
        bool isGi = t < 384;
        int col = isGi ? t : t - 384;
        const float* Wt  = isGi ? Wvih : WhhT;
        const float* src = isGi ? y_lds : p_lds;
        float g0 = isGi ? bvih[col] : bhh[col];
        for (int d4 = 0; d4 < DD / 4; d4++) {
            float4 v = *(const float4*)&src[d4 * 4];
            const float* wp = Wt + (size_t)(d4 * 4) * 3 * DD + col;
            g0 += v.x * wp[0] + v.y * wp[3 * DD] + v.z * wp[6 * DD] + v.w * wp[9 * DD];
        }
        if (isGi) gi_lds[col] = g0; else gh_lds[col] = g0;
    }
    __syncthreads();

    float snew = 0.f;
    if (t < DD) {
        float r = 1.f / (1.f + __expf(-(gi_lds[t] + gh_lds[t])));
        float z = 1.f / (1.f + __expf(-(gi_lds[DD + t] + gh_lds[DD + t])));
        float nn_ = tanhf(gi_lds[2 * DD + t] + r * gh_lds[2 * DD + t]);
        snew = (1.f - z) * nn_ + z * prev;
    }
    // --- LN(snew) ---
    {
        float s_ = (t < DD) ? snew : 0.f, sq_ = s_ * s_;
        #pragma unroll
        for (int o = 32; o > 0; o >>= 1) { s_ += __shfl_xor(s_, o); sq_ += __shfl_xor(sq_, o); }
        if (t < DD && (t & 63) == 0) { red[(t >> 6) * 2] = s_; red[(t >> 6) * 2 + 1] = sq_; }
    }
    __syncthreads();
    if (t < DD) {
        float mean = (red[0] + red[2]) * (1.0f / DD);
        float var  = (red[1] + red[3]) * (1.0f / DD) - mean * mean;
        float rstd = rsqrtf(var + LN_EPS);
        tmp[t] = (snew - mean) * rstd * g_ff[t] + b_ff[t];
    }
    __syncthreads();
    // --- W1 matvec, 4-way split over d ---
    {
        int g = t >> 7, c = t & 127;
        if (g < 4) {
            float hp = 0.f;
            for (int d4 = g * 8; d4 < g * 8 + 8; d4++) {
                float4 tv = *(const float4*)&tmp[d4 * 4];
                const float* wp = W1 + (size_t)(d4 * 4) * DD + c;
                hp += tv.x * wp[0] + tv.y * wp[DD] + tv.z * wp[2 * DD] + tv.w * wp[3 * DD];
            }
            pp[g][c] = hp;
        }
    }
    __syncthreads();
    if (t < DD)
        tmp[t] = fmaxf(pp[0][t] + pp[1][t] + pp[2][t] + pp[3][t] + b1[t], 0.f);
    __syncthreads();
    // --- W2 matvec, 4-way split ---
    {
        int g = t >> 7, c = t & 127;
        if (g < 4) {
            float hp = 0.f;
            for (int d4 = g * 8; d4 < g * 8 + 8; d4++) {
                float4 tv = *(const float4*)&tmp[d4 * 4];
                const float* wp = W2 + (size_t)(d4 * 4) * DD + c;
                hp += tv.x * wp[0] + tv.y * wp[DD] + tv.z * wp[2 * DD] + tv.w * wp[3 * DD];
            }
            pp[g][c] = hp;
        }
    }
    __syncthreads();
    float o = 0.f;
    if (t < DD) {
        o = snew + b2[t] + pp[0][t] + pp[1][t] + pp[2][t] + pp[3][t];
        slots[(b * KK + kslot) * DD + t] = o;
    }
    // --- LN(o) ---
    {
        float s_ = (t < DD) ? o : 0.f, sq_ = s_ * s_;
        #pragma unroll
        for (int o2 = 32; o2 > 0; o2 >>= 1) { s_ += __shfl_xor(s_, o2); sq_ += __shfl_xor(sq_, o2); }
        if (t < DD && (t & 63) == 0) { red[(t >> 6) * 2] = s_; red[(t >> 6) * 2 + 1] = sq_; }
    }
    __syncthreads();
    if (t < DD) {
        float mean = (red[0] + red[2]) * (1.0f / DD);
        float var  = (red[1] + red[3]) * (1.0f / DD) - mean * mean;
        float rstd = rsqrtf(var + LN_EPS);
        tmp[t] = (o - mean) * rstd * g_sl[t] + b_sl[t];
    }
    __syncthreads();
    // --- M matvec, 4-way split ---
    {
        int g = t >> 7, c = t & 127;
        if (g < 4) {
            float hp = 0.f;
            for (int d4 = g * 8; d4 < g * 8 + 8; d4++) {
                float4 tv = *(const float4*)&tmp[d4 * 4];
                const float* wp = M + (size_t)(d4 * 4) * DD + c;
                hp += tv.x * wp[0] + tv.y * wp[DD] + tv.z * wp[2 * DD] + tv.w * wp[3 * DD];
            }
            pp[g][c] = hp;
        }
    }
    __syncthreads();
    if (t < DD) {
        float qq = v0[t] + pp[0][t] + pp[1][t] + pp[2][t] + pp[3][t];
        qp[(b * KK + kslot) * DD + t] = SCALE * qq;
        if (last) {
            out_nf[(b * KK + kslot) * DD + t] = o;
            if (t < KK) out_adj[(b * KK + kslot) * KK + t] = 1.0f;
        }
    }
    {
        float cp = (t < DD) ? tmp[t] * wqbk[t] : 0.f;
        #pragma unroll
        for (int o2 = 32; o2 > 0; o2 >>= 1) cp += __shfl_xor(cp, o2);
        if (t < 128 && (t & 63) == 0) red[4 + (t >> 6)] = cp;
    }
    __syncthreads();
    if (t == 0) qc0[b * KK + kslot] = SCALE * (red[4] + red[5] + c1[0]);
}

// ------------------------------------------------------------------
extern "C" void kernel_launch(void* const* d_in, const int* in_sizes, int n_in,
                              void* d_out, int out_size, void* d_ws, size_t ws_size,
                              hipStream_t stream) {
    (void)in_sizes; (void)n_in; (void)out_size; (void)ws_size;
    const float* x        = (const float*)d_in[0];
    const float* noise    = (const float*)d_in[1];
    const float* mu       = (const float*)d_in[2];
    const float* logsigma = (const float*)d_in[3];
    const float* Wq  = (const float*)d_in[4];
    const float* bq  = (const float*)d_in[5];
    const float* Wk  = (const float*)d_in[6];
    const float* bk  = (const float*)d_in[7];
    const float* Wv  = (const float*)d_in[8];
    const float* bv  = (const float*)d_in[9];
    const float* Wih = (const float*)d_in[10];
    const float* Whh = (const float*)d_in[11];
    const float* bih = (const float*)d_in[12];
    const float* bhh = (const float*)d_in[13];
    const float* W1  = (const float*)d_in[14];
    const float* b1  = (const float*)d_in[15];
    const float* W2  = (const float*)d_in[16];
    const float* b2  = (const float*)d_in[17];
    const float* g_in = (const float*)d_in[18];
    const float* b_in = (const float*)d_in[19];
    const float* g_sl = (const float*)d_in[20];
    const float* b_sl = (const float*)d_in[21];
    const float* g_ff = (const float*)d_in[22];
    const float* b_ff = (const float*)d_in[23];

    float* w = (float*)d_ws;
    ushort* xn   = (ushort*)(w + OFF_XN);
    float* qp    = w + OFF_Q;
    float* qc0   = w + OFF_QC0;
    float* slots = w + OFF_SLOTS;
    float* upart = w + OFF_UPART;
    float* dpart = w + OFF_DPART;
    float* sxp   = w + OFF_SXP;
    float* sumx  = w + OFF_SUMX;
    float* WihT  = w + OFF_WIHT;
    float* WhhT  = w + OFF_WHHT;
    float* Wvih  = w + OFF_WVIH;
    float* bvih  = w + OFF_BVIH;
    float* Mw    = w + OFF_M;
    float* v0    = w + OFF_V0;
    float* wqbk  = w + OFF_WQBK;
    float* c1    = w + OFF_C1;

    float* out_nf  = (float*)d_out;                       // [B,K,D]
    float* out_adj = out_nf + BB * KK * DD;               // [B,K,K]
    float* out_s   = out_adj + BB * KK * KK;              // [B,N,K]

    k_prep<<<(PREP_TOTAL + 255) / 256, 256, 0, stream>>>(
        Wih, Whh, Wq, Wk, Wv, bih, bv, bq, bk,
        WihT, WhhT, Wvih, bvih, Mw, v0, wqbk, c1);
    k_ln<<<BB * LNCH, 256, 0, stream>>>(x, g_in, b_in, xn, sxp);
    k_sumx<<<BB, 512, 0, stream>>>(sxp, sumx);
    k_init<<<BB * KK, 128, 0, stream>>>(noise, mu, logsigma, Mw, v0, wqbk, c1,
                                        g_sl, b_sl, slots, qp, qc0);

    for (int it = 0; it < N_ITERS; it++) {
        int last = (it == N_ITERS - 1) ? 1 : 0;
        k_attn<<<BB * NCH, 256, 0, stream>>>(xn, qp, qc0, upart, dpart,
                                             out_s, last);
        k_slot<<<BB * KK, 768, 0, stream>>>(upart, dpart, sumx,
                                            Wvih, bvih, WhhT, bhh, W1, b1, W2, b2,
                                            Mw, v0, wqbk, c1, g_ff, b_ff, g_sl, b_sl,
                                            slots, qp, qc0, out_nf, out_adj, last);
    }
}